// Round 1
// baseline (2434.267 us; speedup 1.0000x reference)
//
#include <hip/hip_runtime.h>

#define N_PIX 65536  // 256*256

// ---------------- ws layout (float offsets) ----------------
#define OFF_QPRE   0u          // [4][64][65536]
#define OFF_KVPRE  16777216u   // [4][128][65536]
#define OFF_S      50331648u   // [4][8][8][8]
#define OFF_SQ     50333696u   // [4][64]
#define OFF_SK     50333952u   // [4][64]
#define OFF_MT     50334208u   // [4][64][64]  (dg-major, o contiguous)
#define OFF_WQT    50350592u   // [64][64]   Wq^T * ln1x_w
#define OFF_BQ     50354688u   // [64]
#define OFF_CQ     50354752u   // [64]
#define OFF_WKVT   50354816u   // [64][128]  Wkv^T * ln1y_w
#define OFF_BKV    50363008u   // [128]
#define OFF_CKV    50363136u   // [128]
#define OFF_W3T    50363264u   // [170][64]  W3^T
// total 50374144 floats = 201,496,576 bytes

__device__ __forceinline__ float dw3x3(const float* __restrict__ p,
                                       const float* __restrict__ w,
                                       int n, bool ym, bool yp, bool xm, bool xp) {
  float a = p[n] * w[4];
  if (ym) {
    if (xm) a = fmaf(p[n - 257], w[0], a);
    a = fmaf(p[n - 256], w[1], a);
    if (xp) a = fmaf(p[n - 255], w[2], a);
  }
  if (xm) a = fmaf(p[n - 1], w[3], a);
  if (xp) a = fmaf(p[n + 1], w[5], a);
  if (yp) {
    if (xm) a = fmaf(p[n + 255], w[6], a);
    a = fmaf(p[n + 256], w[7], a);
    if (xp) a = fmaf(p[n + 257], w[8], a);
  }
  return a;
}

__device__ __forceinline__ float wred(float v) {
#pragma unroll
  for (int m = 32; m >= 1; m >>= 1) v += __shfl_xor(v, m, 64);
  return v;
}

// ---------------- K0: weight prep ----------------
__global__ __launch_bounds__(256) void k_prep(
    const float* __restrict__ Wq, const float* __restrict__ ln1xw, const float* __restrict__ ln1xb,
    const float* __restrict__ Wkv, const float* __restrict__ ln1yw, const float* __restrict__ ln1yb,
    const float* __restrict__ W3, float* __restrict__ ws) {
  int tid = threadIdx.x;
  float* Wqt = ws + OFF_WQT; float* Bq = ws + OFF_BQ; float* Cq = ws + OFF_CQ;
  float* Wkvt = ws + OFF_WKVT; float* Bkv = ws + OFF_BKV; float* Ckv = ws + OFF_CKV;
  float* W3t = ws + OFF_W3T;
  for (int i = tid; i < 4096; i += 256) {
    int c = i >> 6, o = i & 63;
    Wqt[c * 64 + o] = Wq[o * 64 + c] * ln1xw[c];
  }
  for (int i = tid; i < 8192; i += 256) {
    int c = i >> 7, o = i & 127;
    Wkvt[c * 128 + o] = Wkv[o * 64 + c] * ln1yw[c];
  }
  for (int i = tid; i < 10880; i += 256) {
    int j = i >> 6, o = i & 63;
    W3t[j * 64 + o] = W3[o * 170 + j];
  }
  if (tid < 64) {
    float bq = 0.f, cq = 0.f;
    for (int c = 0; c < 64; c++) {
      bq = fmaf(Wq[tid * 64 + c], ln1xw[c], bq);
      cq = fmaf(Wq[tid * 64 + c], ln1xb[c], cq);
    }
    Bq[tid] = bq; Cq[tid] = cq;
  }
  if (tid < 128) {
    float bk = 0.f, ck = 0.f;
    for (int c = 0; c < 64; c++) {
      bk = fmaf(Wkv[tid * 64 + c], ln1yw[c], bk);
      ck = fmaf(Wkv[tid * 64 + c], ln1yb[c], ck);
    }
    Bkv[tid] = bk; Ckv[tid] = ck;
  }
}

// ---------------- K1: fused LN + 1x1 conv (single pass) ----------------
// out[o] = rs*(sum_c Wt[c][o]*x[c]) - rs*mu*B[o] + C[o]
template <int NOUT>
__global__ __launch_bounds__(256) void k_ln_conv1x1(
    const float* __restrict__ in, const float* __restrict__ Wt,
    const float* __restrict__ Bv, const float* __restrict__ Cv,
    float* __restrict__ outp) {
  int b = blockIdx.x >> 8;
  int n = ((blockIdx.x & 255) << 8) + threadIdx.x;
  const float* px = in + (size_t)b * (64 * N_PIX) + n;
  float acc[NOUT];
#pragma unroll
  for (int o = 0; o < NOUT; o++) acc[o] = 0.f;
  float s1 = 0.f, s2 = 0.f;
#pragma unroll 2
  for (int c = 0; c < 64; c++) {
    float xv = px[(size_t)c << 16];
    s1 += xv;
    s2 = fmaf(xv, xv, s2);
    const float* wrow = Wt + c * NOUT;
#pragma unroll
    for (int o = 0; o < NOUT; o++) acc[o] = fmaf(wrow[o], xv, acc[o]);
  }
  float mu = s1 * 0.015625f;
  float var = fmaf(s2, 0.015625f, -mu * mu);
  float rs = rsqrtf(var + 1e-5f);
  float rm = rs * mu;
  float* po = outp + (size_t)b * (NOUT * N_PIX) + n;
#pragma unroll
  for (int o = 0; o < NOUT; o++) {
    po[(size_t)o << 16] = fmaf(rs, acc[o], fmaf(-rm, Bv[o], Cv[o]));
  }
}

// ---------------- K2: dwconv(q), dwconv(k) on the fly; accumulate S, ||q||^2, ||k||^2 ----------------
__global__ __launch_bounds__(256) void k_qk_stats(
    const float* __restrict__ q_pre, const float* __restrict__ kv_pre,
    const float* __restrict__ Wq_dw, const float* __restrict__ Wkv_dw,
    float* __restrict__ S, float* __restrict__ sq, float* __restrict__ sk) {
  int blk = blockIdx.x;           // 256 blocks: 64 per image, 4 rows each
  int b = blk >> 6;
  int y = ((blk & 63) << 2) + (threadIdx.x >> 6);
  int lane = threadIdx.x & 63;
  bool ym = y > 0, yp = y < 255;
  const float* qb = q_pre + (size_t)b * (64 * N_PIX);
  const float* kb = kv_pre + (size_t)b * (128 * N_PIX);
#pragma unroll 1
  for (int h = 0; h < 8; h++) {
    float prod[8][8], sqp[8], skp[8];
#pragma unroll
    for (int r = 0; r < 8; r++) {
      sqp[r] = 0.f; skp[r] = 0.f;
#pragma unroll
      for (int d = 0; d < 8; d++) prod[r][d] = 0.f;
    }
#pragma unroll 1
    for (int p = 0; p < 4; p++) {
      int x = lane + (p << 6);
      bool xm = x > 0, xpp = x < 255;
      int n = (y << 8) + x;
      float qd[8], kd[8];
#pragma unroll
      for (int rr = 0; rr < 8; rr++) {
        int c = h * 8 + rr;
        qd[rr] = dw3x3(qb + ((size_t)c << 16), Wq_dw + c * 9, n, ym, yp, xm, xpp);
        kd[rr] = dw3x3(kb + ((size_t)c << 16), Wkv_dw + c * 9, n, ym, yp, xm, xpp);
      }
#pragma unroll
      for (int r = 0; r < 8; r++) {
        sqp[r] = fmaf(qd[r], qd[r], sqp[r]);
        skp[r] = fmaf(kd[r], kd[r], skp[r]);
#pragma unroll
        for (int d = 0; d < 8; d++) prod[r][d] = fmaf(qd[r], kd[d], prod[r][d]);
      }
    }
#pragma unroll
    for (int r = 0; r < 8; r++) {
#pragma unroll
      for (int d = 0; d < 8; d++) prod[r][d] = wred(prod[r][d]);
      sqp[r] = wred(sqp[r]);
      skp[r] = wred(skp[r]);
    }
    if (lane == 0) {
      float* Sh = S + ((b * 8 + h) * 8) * 8;
#pragma unroll
      for (int r = 0; r < 8; r++) {
#pragma unroll
        for (int d = 0; d < 8; d++) atomicAdd(&Sh[r * 8 + d], prod[r][d]);
        atomicAdd(&sq[b * 64 + h * 8 + r], sqp[r]);
        atomicAdd(&sk[b * 64 + h * 8 + r], skp[r]);
      }
    }
  }
}

// ---------------- K3: softmax + M_b = Wproj * blockdiag(attn_h) ----------------
__global__ __launch_bounds__(256) void k_attn_mat(
    const float* __restrict__ S, const float* __restrict__ sq, const float* __restrict__ sk,
    const float* __restrict__ temp, const float* __restrict__ Wproj,
    float* __restrict__ Mt) {
  __shared__ float aw[4][8][8][8];
  int tid = threadIdx.x;
  {
    int b = tid >> 6, h = (tid >> 3) & 7, r = tid & 7;
    float qn = fmaxf(sqrtf(sq[b * 64 + h * 8 + r]), 1e-12f);
    float tt = temp[h];
    float lg[8];
    float mx = -1e30f;
#pragma unroll
    for (int d = 0; d < 8; d++) {
      float kn = fmaxf(sqrtf(sk[b * 64 + h * 8 + d]), 1e-12f);
      lg[d] = S[((b * 8 + h) * 8 + r) * 8 + d] / (qn * kn) * tt;
      mx = fmaxf(mx, lg[d]);
    }
    float sm = 0.f;
#pragma unroll
    for (int d = 0; d < 8; d++) { lg[d] = __expf(lg[d] - mx); sm += lg[d]; }
    float inv = 1.f / sm;
#pragma unroll
    for (int d = 0; d < 8; d++) aw[b][h][r][d] = lg[d] * inv;
  }
  __syncthreads();
  {
    int b = tid >> 6, o = tid & 63;
#pragma unroll 1
    for (int h = 0; h < 8; h++) {
#pragma unroll
      for (int d = 0; d < 8; d++) {
        float m = 0.f;
#pragma unroll
        for (int r = 0; r < 8; r++) m = fmaf(Wproj[o * 64 + h * 8 + r], aw[b][h][r][d], m);
        Mt[(size_t)(b * 64 + (h * 8 + d)) * 64 + o] = m;  // [b][dg][o]
      }
    }
  }
}

// ---------------- K4: fused dwconv(v) + M-matvec + residual + LN2 + FFN ----------------
__global__ __launch_bounds__(256) void k_out(
    const float* __restrict__ x, const float* __restrict__ kv_pre,
    const float* __restrict__ Wkv_dw, const float* __restrict__ Mt,
    const float* __restrict__ ln2w, const float* __restrict__ ln2b,
    const float* __restrict__ W12, const float* __restrict__ W3t,
    float* __restrict__ outp) {
  int b = blockIdx.x >> 8;
  int y = blockIdx.x & 255;
  int xcol = threadIdx.x;
  int n = (y << 8) + xcol;
  bool ym = y > 0, yp = y < 255, xm = xcol > 0, xpp = xcol < 255;
  const float* vb = kv_pre + (size_t)b * (128 * N_PIX) + ((size_t)64 << 16);
  const float* Mb = Mt + b * 4096;
  float acc[64];
#pragma unroll
  for (int o = 0; o < 64; o++) acc[o] = 0.f;
#pragma unroll 2
  for (int dg = 0; dg < 64; dg++) {
    float v = dw3x3(vb + ((size_t)dg << 16), Wkv_dw + (64 + dg) * 9, n, ym, yp, xm, xpp);
    const float* mrow = Mb + dg * 64;
#pragma unroll
    for (int o = 0; o < 64; o++) acc[o] = fmaf(mrow[o], v, acc[o]);
  }
  // residual + LN2 stats
  const float* px = x + (size_t)b * (64 * N_PIX) + n;
  float s1 = 0.f, s2 = 0.f;
#pragma unroll
  for (int c = 0; c < 64; c++) {
    float v = px[(size_t)c << 16] + acc[c];
    acc[c] = v;
    s1 += v;
    s2 = fmaf(v, v, s2);
  }
  float mu = s1 * 0.015625f;
  float var = fmaf(s2, 0.015625f, -mu * mu);
  float rs = rsqrtf(var + 1e-5f);
  float facc[64];
#pragma unroll
  for (int c = 0; c < 64; c++) {
    facc[c] = acc[c];                                  // x1 (residual base)
    acc[c] = fmaf((acc[c] - mu) * rs, ln2w[c], ln2b[c]);  // xn2
  }
  // FFN: gated MLP 64 -> 2x170 -> 64
#pragma unroll 2
  for (int j = 0; j < 170; j++) {
    const float* w1 = W12 + j * 64;
    const float* w2 = W12 + (170 + j) * 64;
    float h1a = 0.f, h1b = 0.f, h1c = 0.f, h1d = 0.f;
    float h2a = 0.f, h2b = 0.f, h2c = 0.f, h2d = 0.f;
#pragma unroll
    for (int c = 0; c < 64; c += 4) {
      h1a = fmaf(w1[c], acc[c], h1a);
      h1b = fmaf(w1[c + 1], acc[c + 1], h1b);
      h1c = fmaf(w1[c + 2], acc[c + 2], h1c);
      h1d = fmaf(w1[c + 3], acc[c + 3], h1d);
      h2a = fmaf(w2[c], acc[c], h2a);
      h2b = fmaf(w2[c + 1], acc[c + 1], h2b);
      h2c = fmaf(w2[c + 2], acc[c + 2], h2c);
      h2d = fmaf(w2[c + 3], acc[c + 3], h2d);
    }
    float h1 = (h1a + h1b) + (h1c + h1d);
    float h2 = (h2a + h2b) + (h2c + h2d);
    float g = h1 * __builtin_amdgcn_rcpf(1.f + __expf(-h1)) * h2;  // silu(h1)*h2
    const float* w3r = W3t + j * 64;
#pragma unroll
    for (int o = 0; o < 64; o++) facc[o] = fmaf(w3r[o], g, facc[o]);
  }
  float* po = outp + (size_t)b * (64 * N_PIX) + n;
#pragma unroll
  for (int c = 0; c < 64; c++) po[(size_t)c << 16] = facc[c];
}

extern "C" void kernel_launch(void* const* d_in, const int* in_sizes, int n_in,
                              void* d_out, int out_size, void* d_ws, size_t ws_size,
                              hipStream_t stream) {
  const float* x      = (const float*)d_in[0];
  const float* y      = (const float*)d_in[1];
  const float* ln1xw  = (const float*)d_in[2];
  const float* ln1xb  = (const float*)d_in[3];
  const float* ln1yw  = (const float*)d_in[4];
  const float* ln1yb  = (const float*)d_in[5];
  const float* ln2w   = (const float*)d_in[6];
  const float* ln2b   = (const float*)d_in[7];
  const float* Wq     = (const float*)d_in[8];
  const float* Wq_dw  = (const float*)d_in[9];
  const float* Wkv    = (const float*)d_in[10];
  const float* Wkv_dw = (const float*)d_in[11];
  const float* Wproj  = (const float*)d_in[12];
  const float* temp   = (const float*)d_in[13];
  const float* W12    = (const float*)d_in[14];
  const float* W3     = (const float*)d_in[15];
  float* out = (float*)d_out;
  float* ws = (float*)d_ws;

  float* q_pre  = ws + OFF_QPRE;
  float* kv_pre = ws + OFF_KVPRE;
  float* Sb     = ws + OFF_S;
  float* sqb    = ws + OFF_SQ;
  float* skb    = ws + OFF_SK;
  float* Mt     = ws + OFF_MT;

  hipMemsetAsync(Sb, 0, 2560 * sizeof(float), stream);  // S + sq + sk contiguous
  k_prep<<<1, 256, 0, stream>>>(Wq, ln1xw, ln1xb, Wkv, ln1yw, ln1yb, W3, ws);
  k_ln_conv1x1<64><<<1024, 256, 0, stream>>>(x, ws + OFF_WQT, ws + OFF_BQ, ws + OFF_CQ, q_pre);
  k_ln_conv1x1<128><<<1024, 256, 0, stream>>>(y, ws + OFF_WKVT, ws + OFF_BKV, ws + OFF_CKV, kv_pre);
  k_qk_stats<<<256, 256, 0, stream>>>(q_pre, kv_pre, Wq_dw, Wkv_dw, Sb, sqb, skb);
  k_attn_mat<<<1, 256, 0, stream>>>(Sb, sqb, skb, temp, Wproj, Mt);
  k_out<<<1024, 256, 0, stream>>>(x, kv_pre, Wkv_dw, Mt, ln2w, ln2b, W12, ws + OFF_W3T, out);
}

// Round 2
// 1566.138 us; speedup vs baseline: 1.5543x; 1.5543x over previous
//
#include <hip/hip_runtime.h>

#define N_PIX 65536  // 256*256

// ---------------- ws layout (float offsets) ----------------
#define OFF_QPRE   0u          // [4][64][65536]
#define OFF_KVPRE  16777216u   // [4][128][65536]
#define OFF_S      50331648u   // [4][8][8][8]
#define OFF_SQ     50333696u   // [4][64]
#define OFF_SK     50333952u   // [4][64]
#define OFF_MT     50334208u   // [4][64][64]  (dg-major, o contiguous)
#define OFF_WQT    50350592u   // [64][64]   Wq^T * ln1x_w
#define OFF_BQ     50354688u   // [64]
#define OFF_CQ     50354752u   // [64]
#define OFF_WKVT   50354816u   // [64][128]  Wkv^T * ln1y_w
#define OFF_BKV    50363008u   // [128]
#define OFF_CKV    50363136u   // [128]
#define OFF_W3T    50363264u   // [170][64]  W3^T
// total 50374144 floats = 201,496,576 bytes

__device__ __forceinline__ float dw3x3(const float* __restrict__ p,
                                       const float* __restrict__ w,
                                       int n, bool ym, bool yp, bool xm, bool xp) {
  float a = p[n] * w[4];
  if (ym) {
    if (xm) a = fmaf(p[n - 257], w[0], a);
    a = fmaf(p[n - 256], w[1], a);
    if (xp) a = fmaf(p[n - 255], w[2], a);
  }
  if (xm) a = fmaf(p[n - 1], w[3], a);
  if (xp) a = fmaf(p[n + 1], w[5], a);
  if (yp) {
    if (xm) a = fmaf(p[n + 255], w[6], a);
    a = fmaf(p[n + 256], w[7], a);
    if (xp) a = fmaf(p[n + 257], w[8], a);
  }
  return a;
}

__device__ __forceinline__ float wred(float v) {
#pragma unroll
  for (int m = 32; m >= 1; m >>= 1) v += __shfl_xor(v, m, 64);
  return v;
}

// ---------------- K0: weight prep ----------------
__global__ __launch_bounds__(256) void k_prep(
    const float* __restrict__ Wq, const float* __restrict__ ln1xw, const float* __restrict__ ln1xb,
    const float* __restrict__ Wkv, const float* __restrict__ ln1yw, const float* __restrict__ ln1yb,
    const float* __restrict__ W3, float* __restrict__ ws) {
  int tid = threadIdx.x;
  float* Wqt = ws + OFF_WQT; float* Bq = ws + OFF_BQ; float* Cq = ws + OFF_CQ;
  float* Wkvt = ws + OFF_WKVT; float* Bkv = ws + OFF_BKV; float* Ckv = ws + OFF_CKV;
  float* W3t = ws + OFF_W3T;
  for (int i = tid; i < 4096; i += 256) {
    int c = i >> 6, o = i & 63;
    Wqt[c * 64 + o] = Wq[o * 64 + c] * ln1xw[c];
  }
  for (int i = tid; i < 8192; i += 256) {
    int c = i >> 7, o = i & 127;
    Wkvt[c * 128 + o] = Wkv[o * 64 + c] * ln1yw[c];
  }
  for (int i = tid; i < 10880; i += 256) {
    int j = i >> 6, o = i & 63;
    W3t[j * 64 + o] = W3[o * 170 + j];
  }
  if (tid < 64) {
    float bq = 0.f, cq = 0.f;
    for (int c = 0; c < 64; c++) {
      bq = fmaf(Wq[tid * 64 + c], ln1xw[c], bq);
      cq = fmaf(Wq[tid * 64 + c], ln1xb[c], cq);
    }
    Bq[tid] = bq; Cq[tid] = cq;
  }
  if (tid < 128) {
    float bk = 0.f, ck = 0.f;
    for (int c = 0; c < 64; c++) {
      bk = fmaf(Wkv[tid * 64 + c], ln1yw[c], bk);
      ck = fmaf(Wkv[tid * 64 + c], ln1yb[c], ck);
    }
    Bkv[tid] = bk; Ckv[tid] = ck;
  }
}

// ---------------- K1: fused LN + 1x1 conv (single pass) ----------------
// out[o] = rs*(sum_c Wt[c][o]*x[c]) - rs*mu*B[o] + C[o]
// wstride: row stride of Wt; bstride: channel count of output tensor per batch.
template <int NOUT>
__global__ __launch_bounds__(256) void k_ln_conv1x1(
    const float* __restrict__ in, const float* __restrict__ Wt, int wstride,
    const float* __restrict__ Bv, const float* __restrict__ Cv,
    float* __restrict__ outp, int bstride) {
  int b = blockIdx.x >> 8;
  int n = ((blockIdx.x & 255) << 8) + threadIdx.x;
  const float* px = in + (size_t)b * (64 * N_PIX) + n;
  float acc[NOUT];
#pragma unroll
  for (int o = 0; o < NOUT; o++) acc[o] = 0.f;
  float s1 = 0.f, s2 = 0.f;
#pragma unroll 2
  for (int c = 0; c < 64; c++) {
    float xv = px[(size_t)c << 16];
    s1 += xv;
    s2 = fmaf(xv, xv, s2);
    const float* wrow = Wt + c * wstride;
#pragma unroll
    for (int o = 0; o < NOUT; o++) acc[o] = fmaf(wrow[o], xv, acc[o]);
  }
  float mu = s1 * 0.015625f;
  float var = fmaf(s2, 0.015625f, -mu * mu);
  float rs = rsqrtf(var + 1e-5f);
  float rm = rs * mu;
  float* po = outp + (size_t)b * ((size_t)bstride * N_PIX) + n;
#pragma unroll
  for (int o = 0; o < NOUT; o++) {
    po[(size_t)o << 16] = fmaf(rs, acc[o], fmaf(-rm, Bv[o], Cv[o]));
  }
}

// ---------------- K2: dwconv(q), dwconv(k) on the fly; accumulate S, ||q||^2, ||k||^2 ----------------
// grid: 4b * 8h * 64 row-groups = 2048 blocks; block = 4 rows x 64 lanes
__global__ __launch_bounds__(256) void k_qk_stats(
    const float* __restrict__ q_pre, const float* __restrict__ kv_pre,
    const float* __restrict__ Wq_dw, const float* __restrict__ Wkv_dw,
    float* __restrict__ S, float* __restrict__ sq, float* __restrict__ sk) {
  int blk = blockIdx.x;
  int b = blk >> 9;
  int h = (blk >> 6) & 7;
  int rg = blk & 63;
  int tid = threadIdx.x;
  int wave = tid >> 6;
  int lane = tid & 63;
  int y = (rg << 2) + wave;
  bool ym = y > 0, yp = y < 255;
  const float* qb = q_pre + (size_t)b * (64 * N_PIX);
  const float* kb = kv_pre + (size_t)b * (128 * N_PIX);

  float prod[8][8], sqp[8], skp[8];
#pragma unroll
  for (int r = 0; r < 8; r++) {
    sqp[r] = 0.f; skp[r] = 0.f;
#pragma unroll
    for (int d = 0; d < 8; d++) prod[r][d] = 0.f;
  }
#pragma unroll 1
  for (int p = 0; p < 4; p++) {
    int x = lane + (p << 6);
    bool xm = x > 0, xpp = x < 255;
    int n = (y << 8) + x;
    float qd[8], kd[8];
#pragma unroll
    for (int rr = 0; rr < 8; rr++) {
      int c = h * 8 + rr;
      qd[rr] = dw3x3(qb + ((size_t)c << 16), Wq_dw + c * 9, n, ym, yp, xm, xpp);
      kd[rr] = dw3x3(kb + ((size_t)c << 16), Wkv_dw + c * 9, n, ym, yp, xm, xpp);
    }
#pragma unroll
    for (int r = 0; r < 8; r++) {
      sqp[r] = fmaf(qd[r], qd[r], sqp[r]);
      skp[r] = fmaf(kd[r], kd[r], skp[r]);
#pragma unroll
      for (int d = 0; d < 8; d++) prod[r][d] = fmaf(qd[r], kd[d], prod[r][d]);
    }
  }
  // in-wave butterfly reduce, then cross-wave LDS reduce, then 80 atomics/block
  __shared__ float red[4][80];
#pragma unroll
  for (int r = 0; r < 8; r++) {
#pragma unroll
    for (int d = 0; d < 8; d++) {
      float v = wred(prod[r][d]);
      if (lane == 0) red[wave][r * 8 + d] = v;
    }
    float vq = wred(sqp[r]);
    float vk = wred(skp[r]);
    if (lane == 0) { red[wave][64 + r] = vq; red[wave][72 + r] = vk; }
  }
  __syncthreads();
  if (tid < 80) {
    float s = red[0][tid] + red[1][tid] + red[2][tid] + red[3][tid];
    if (tid < 64) atomicAdd(&S[(b * 8 + h) * 64 + tid], s);
    else if (tid < 72) atomicAdd(&sq[b * 64 + h * 8 + (tid - 64)], s);
    else atomicAdd(&sk[b * 64 + h * 8 + (tid - 72)], s);
  }
}

// ---------------- K3: softmax + M_b = Wproj * blockdiag(attn_h) ----------------
__global__ __launch_bounds__(256) void k_attn_mat(
    const float* __restrict__ S, const float* __restrict__ sq, const float* __restrict__ sk,
    const float* __restrict__ temp, const float* __restrict__ Wproj,
    float* __restrict__ Mt) {
  __shared__ float aw[4][8][8][8];
  int tid = threadIdx.x;
  {
    int b = tid >> 6, h = (tid >> 3) & 7, r = tid & 7;
    float qn = fmaxf(sqrtf(sq[b * 64 + h * 8 + r]), 1e-12f);
    float tt = temp[h];
    float lg[8];
    float mx = -1e30f;
#pragma unroll
    for (int d = 0; d < 8; d++) {
      float kn = fmaxf(sqrtf(sk[b * 64 + h * 8 + d]), 1e-12f);
      lg[d] = S[((b * 8 + h) * 8 + r) * 8 + d] / (qn * kn) * tt;
      mx = fmaxf(mx, lg[d]);
    }
    float sm = 0.f;
#pragma unroll
    for (int d = 0; d < 8; d++) { lg[d] = __expf(lg[d] - mx); sm += lg[d]; }
    float inv = 1.f / sm;
#pragma unroll
    for (int d = 0; d < 8; d++) aw[b][h][r][d] = lg[d] * inv;
  }
  __syncthreads();
  {
    int b = tid >> 6, o = tid & 63;
#pragma unroll 1
    for (int h = 0; h < 8; h++) {
#pragma unroll
      for (int d = 0; d < 8; d++) {
        float m = 0.f;
#pragma unroll
        for (int r = 0; r < 8; r++) m = fmaf(Wproj[o * 64 + h * 8 + r], aw[b][h][r][d], m);
        Mt[(size_t)(b * 64 + (h * 8 + d)) * 64 + o] = m;  // [b][dg][o]
      }
    }
  }
}

// ---------------- K4: fused dwconv(v) + M-matvec + residual + LN2 + FFN ----------------
__global__ __launch_bounds__(256) void k_out(
    const float* __restrict__ x, const float* __restrict__ kv_pre,
    const float* __restrict__ Wkv_dw, const float* __restrict__ Mt,
    const float* __restrict__ ln2w, const float* __restrict__ ln2b,
    const float* __restrict__ W12, const float* __restrict__ W3t,
    float* __restrict__ outp) {
  int b = blockIdx.x >> 8;
  int y = blockIdx.x & 255;
  int xcol = threadIdx.x;
  int n = (y << 8) + xcol;
  bool ym = y > 0, yp = y < 255, xm = xcol > 0, xpp = xcol < 255;
  const float* vb = kv_pre + (size_t)b * (128 * N_PIX) + ((size_t)64 << 16);
  const float* Mb = Mt + b * 4096;
  float acc[64];
#pragma unroll
  for (int o = 0; o < 64; o++) acc[o] = 0.f;
#pragma unroll 2
  for (int dg = 0; dg < 64; dg++) {
    float v = dw3x3(vb + ((size_t)dg << 16), Wkv_dw + (64 + dg) * 9, n, ym, yp, xm, xpp);
    const float* mrow = Mb + dg * 64;
#pragma unroll
    for (int o = 0; o < 64; o++) acc[o] = fmaf(mrow[o], v, acc[o]);
  }
  // residual + LN2 stats
  const float* px = x + (size_t)b * (64 * N_PIX) + n;
  float s1 = 0.f, s2 = 0.f;
#pragma unroll
  for (int c = 0; c < 64; c++) {
    float v = px[(size_t)c << 16] + acc[c];
    acc[c] = v;
    s1 += v;
    s2 = fmaf(v, v, s2);
  }
  float mu = s1 * 0.015625f;
  float var = fmaf(s2, 0.015625f, -mu * mu);
  float rs = rsqrtf(var + 1e-5f);
  float facc[64];
#pragma unroll
  for (int c = 0; c < 64; c++) {
    facc[c] = acc[c];                                  // x1 (residual base)
    acc[c] = fmaf((acc[c] - mu) * rs, ln2w[c], ln2b[c]);  // xn2
  }
  // FFN: gated MLP 64 -> 2x170 -> 64
#pragma unroll 2
  for (int j = 0; j < 170; j++) {
    const float* w1 = W12 + j * 64;
    const float* w2 = W12 + (170 + j) * 64;
    float h1a = 0.f, h1b = 0.f, h1c = 0.f, h1d = 0.f;
    float h2a = 0.f, h2b = 0.f, h2c = 0.f, h2d = 0.f;
#pragma unroll
    for (int c = 0; c < 64; c += 4) {
      h1a = fmaf(w1[c], acc[c], h1a);
      h1b = fmaf(w1[c + 1], acc[c + 1], h1b);
      h1c = fmaf(w1[c + 2], acc[c + 2], h1c);
      h1d = fmaf(w1[c + 3], acc[c + 3], h1d);
      h2a = fmaf(w2[c], acc[c], h2a);
      h2b = fmaf(w2[c + 1], acc[c + 1], h2b);
      h2c = fmaf(w2[c + 2], acc[c + 2], h2c);
      h2d = fmaf(w2[c + 3], acc[c + 3], h2d);
    }
    float h1 = (h1a + h1b) + (h1c + h1d);
    float h2 = (h2a + h2b) + (h2c + h2d);
    float g = h1 * __builtin_amdgcn_rcpf(1.f + __expf(-h1)) * h2;  // silu(h1)*h2
    const float* w3r = W3t + j * 64;
#pragma unroll
    for (int o = 0; o < 64; o++) facc[o] = fmaf(w3r[o], g, facc[o]);
  }
  float* po = outp + (size_t)b * (64 * N_PIX) + n;
#pragma unroll
  for (int c = 0; c < 64; c++) po[(size_t)c << 16] = facc[c];
}

extern "C" void kernel_launch(void* const* d_in, const int* in_sizes, int n_in,
                              void* d_out, int out_size, void* d_ws, size_t ws_size,
                              hipStream_t stream) {
  const float* x      = (const float*)d_in[0];
  const float* y      = (const float*)d_in[1];
  const float* ln1xw  = (const float*)d_in[2];
  const float* ln1xb  = (const float*)d_in[3];
  const float* ln1yw  = (const float*)d_in[4];
  const float* ln1yb  = (const float*)d_in[5];
  const float* ln2w   = (const float*)d_in[6];
  const float* ln2b   = (const float*)d_in[7];
  const float* Wq     = (const float*)d_in[8];
  const float* Wq_dw  = (const float*)d_in[9];
  const float* Wkv    = (const float*)d_in[10];
  const float* Wkv_dw = (const float*)d_in[11];
  const float* Wproj  = (const float*)d_in[12];
  const float* temp   = (const float*)d_in[13];
  const float* W12    = (const float*)d_in[14];
  const float* W3     = (const float*)d_in[15];
  float* out = (float*)d_out;
  float* ws = (float*)d_ws;

  float* q_pre  = ws + OFF_QPRE;
  float* kv_pre = ws + OFF_KVPRE;
  float* Sb     = ws + OFF_S;
  float* sqb    = ws + OFF_SQ;
  float* skb    = ws + OFF_SK;
  float* Mt     = ws + OFF_MT;

  hipMemsetAsync(Sb, 0, 2560 * sizeof(float), stream);  // S + sq + sk contiguous
  k_prep<<<1, 256, 0, stream>>>(Wq, ln1xw, ln1xb, Wkv, ln1yw, ln1yb, W3, ws);
  // q = LN(x)*Wq ; k = LN(y)*Wkv[0:64] ; v = LN(y)*Wkv[64:128]
  k_ln_conv1x1<64><<<1024, 256, 0, stream>>>(x, ws + OFF_WQT, 64, ws + OFF_BQ, ws + OFF_CQ, q_pre, 64);
  k_ln_conv1x1<64><<<1024, 256, 0, stream>>>(y, ws + OFF_WKVT, 128, ws + OFF_BKV, ws + OFF_CKV, kv_pre, 128);
  k_ln_conv1x1<64><<<1024, 256, 0, stream>>>(y, ws + OFF_WKVT + 64, 128, ws + OFF_BKV + 64, ws + OFF_CKV + 64,
                                             kv_pre + ((size_t)64 << 16), 128);
  k_qk_stats<<<2048, 256, 0, stream>>>(q_pre, kv_pre, Wq_dw, Wkv_dw, Sb, sqb, skb);
  k_attn_mat<<<1, 256, 0, stream>>>(Sb, sqb, skb, temp, Wproj, Mt);
  k_out<<<1024, 256, 0, stream>>>(x, kv_pre, Wkv_dw, Mt, ln2w, ln2b, W12, ws + OFF_W3T, out);
}

// Round 3
// 981.785 us; speedup vs baseline: 2.4794x; 1.5952x over previous
//
#include <hip/hip_runtime.h>

#define N_PIX 65536  // 256*256

typedef short bf16x8 __attribute__((ext_vector_type(8)));
typedef float f32x4 __attribute__((ext_vector_type(4)));

// ---------------- ws layout (float offsets) ----------------
#define OFF_QPRE   0u          // [4][64][65536] q_pre; reused as x1 after k_qk_stats
#define OFF_KVPRE  16777216u   // [4][128][65536]; k-half reused as xn2 bf16 after k_qk_stats
#define OFF_S      50331648u   // [4][8][8][8]
#define OFF_SQ     50333696u   // [4][64]
#define OFF_SK     50333952u   // [4][64]
#define OFF_MT     50334208u   // [4][64][64]  (dg-major, o contiguous)
#define OFF_WQT    50350592u   // [64][64]   Wq^T * ln1x_w
#define OFF_BQ     50354688u   // [64]
#define OFF_CQ     50354752u   // [64]
#define OFF_WKVT   50354816u   // [64][128]  Wkv^T * ln1y_w
#define OFF_BKV    50363008u   // [128]
#define OFF_CKV    50363136u   // [128]
#define OFF_W12S   50363264u   // 22528 bf16 (11264 f): pre-fragmented W12 for MFMA
#define OFF_W3S    50374528u   // 12288 bf16 (6144 f): pre-fragmented W3 for MFMA
// total 50380672 floats = 201,522,688 bytes

__device__ __forceinline__ unsigned short f2bf(float f) {
  unsigned int u = __float_as_uint(f);
  unsigned int r = (u + 0x7FFFu + ((u >> 16) & 1u)) >> 16;
  return (unsigned short)r;
}
__device__ __forceinline__ unsigned int pk2(float a, float b) {
  return (unsigned int)f2bf(a) | ((unsigned int)f2bf(b) << 16);
}

__device__ __forceinline__ float dw3x3(const float* __restrict__ p,
                                       const float* __restrict__ w,
                                       int n, bool ym, bool yp, bool xm, bool xp) {
  float a = p[n] * w[4];
  if (ym) {
    if (xm) a = fmaf(p[n - 257], w[0], a);
    a = fmaf(p[n - 256], w[1], a);
    if (xp) a = fmaf(p[n - 255], w[2], a);
  }
  if (xm) a = fmaf(p[n - 1], w[3], a);
  if (xp) a = fmaf(p[n + 1], w[5], a);
  if (yp) {
    if (xm) a = fmaf(p[n + 255], w[6], a);
    a = fmaf(p[n + 256], w[7], a);
    if (xp) a = fmaf(p[n + 257], w[8], a);
  }
  return a;
}

__device__ __forceinline__ float wred(float v) {
#pragma unroll
  for (int m = 32; m >= 1; m >>= 1) v += __shfl_xor(v, m, 64);
  return v;
}

// ---------------- K0: weight prep (parallel) ----------------
__global__ __launch_bounds__(256) void k_prep(
    const float* __restrict__ Wq, const float* __restrict__ ln1xw, const float* __restrict__ ln1xb,
    const float* __restrict__ Wkv, const float* __restrict__ ln1yw, const float* __restrict__ ln1yb,
    const float* __restrict__ W12, const float* __restrict__ W3, float* __restrict__ ws) {
  int gtid = blockIdx.x * 256 + threadIdx.x;
  int gstride = gridDim.x * 256;
  float* Wqt = ws + OFF_WQT; float* Bq = ws + OFF_BQ; float* Cq = ws + OFF_CQ;
  float* Wkvt = ws + OFF_WKVT; float* Bkv = ws + OFF_BKV; float* Ckv = ws + OFF_CKV;
  unsigned short* W12s = (unsigned short*)(ws + OFF_W12S);
  unsigned short* W3s = (unsigned short*)(ws + OFF_W3S);
  for (int i = gtid; i < 4096; i += gstride) {
    int c = i >> 6, o = i & 63;
    Wqt[c * 64 + o] = Wq[o * 64 + c] * ln1xw[c];
  }
  for (int i = gtid; i < 8192; i += gstride) {
    int c = i >> 7, o = i & 127;
    Wkvt[c * 128 + o] = Wkv[o * 64 + c] * ln1yw[c];
  }
  // W12 fragments: frag fi = ntg*2+kk, ntg 0..21 (0..10 -> W1 tiles, 11..21 -> W2 tiles)
  // element i = ((fi*64 + lane)*8 + e); value = W12[half*170 + j][k], j = ntl*16+(lane&15),
  // k = kk*32 + 8*(lane>>4) + e ; zero-pad j >= 170.
  for (int i = gtid; i < 22528; i += gstride) {
    int e = i & 7, lane = (i >> 3) & 63, fi = i >> 9;
    int kk = fi & 1, ntg = fi >> 1;
    int half = ntg / 11, ntl = ntg % 11;
    int j = ntl * 16 + (lane & 15);
    int k = kk * 32 + ((lane >> 4) << 3) + e;
    float v = (j < 170) ? W12[(half * 170 + j) * 64 + k] : 0.f;
    W12s[i] = f2bf(v);
  }
  // W3 fragments: fi = nt2*6+kk; value = W3[o][k], o = nt2*16+(lane&15), k = kk*32+8*(lane>>4)+e,
  // zero-pad k >= 170.
  for (int i = gtid; i < 12288; i += gstride) {
    int e = i & 7, lane = (i >> 3) & 63, fi = i >> 9;
    int kk = fi % 6, nt2 = fi / 6;
    int o = nt2 * 16 + (lane & 15);
    int k = kk * 32 + ((lane >> 4) << 3) + e;
    float v = (k < 170) ? W3[o * 170 + k] : 0.f;
    W3s[i] = f2bf(v);
  }
  if (gtid < 64) {
    float bq = 0.f, cq = 0.f;
    for (int c = 0; c < 64; c++) {
      bq = fmaf(Wq[gtid * 64 + c], ln1xw[c], bq);
      cq = fmaf(Wq[gtid * 64 + c], ln1xb[c], cq);
    }
    Bq[gtid] = bq; Cq[gtid] = cq;
  }
  if (gtid >= 64 && gtid < 192) {
    int t = gtid - 64;
    float bk = 0.f, ck = 0.f;
    for (int c = 0; c < 64; c++) {
      bk = fmaf(Wkv[t * 64 + c], ln1yw[c], bk);
      ck = fmaf(Wkv[t * 64 + c], ln1yb[c], ck);
    }
    Bkv[t] = bk; Ckv[t] = ck;
  }
}

// ---------------- K1: fused LN + 1x1 conv (single pass) ----------------
template <int NOUT>
__global__ __launch_bounds__(256) void k_ln_conv1x1(
    const float* __restrict__ in, const float* __restrict__ Wt, int wstride,
    const float* __restrict__ Bv, const float* __restrict__ Cv,
    float* __restrict__ outp, int bstride) {
  int b = blockIdx.x >> 8;
  int n = ((blockIdx.x & 255) << 8) + threadIdx.x;
  const float* px = in + (size_t)b * (64 * N_PIX) + n;
  float acc[NOUT];
#pragma unroll
  for (int o = 0; o < NOUT; o++) acc[o] = 0.f;
  float s1 = 0.f, s2 = 0.f;
#pragma unroll 2
  for (int c = 0; c < 64; c++) {
    float xv = px[(size_t)c << 16];
    s1 += xv;
    s2 = fmaf(xv, xv, s2);
    const float* wrow = Wt + c * wstride;
#pragma unroll
    for (int o = 0; o < NOUT; o++) acc[o] = fmaf(wrow[o], xv, acc[o]);
  }
  float mu = s1 * 0.015625f;
  float var = fmaf(s2, 0.015625f, -mu * mu);
  float rs = rsqrtf(var + 1e-5f);
  float rm = rs * mu;
  float* po = outp + (size_t)b * ((size_t)bstride * N_PIX) + n;
#pragma unroll
  for (int o = 0; o < NOUT; o++) {
    po[(size_t)o << 16] = fmaf(rs, acc[o], fmaf(-rm, Bv[o], Cv[o]));
  }
}

// ---------------- K2: qk stats ----------------
__global__ __launch_bounds__(256) void k_qk_stats(
    const float* __restrict__ q_pre, const float* __restrict__ kv_pre,
    const float* __restrict__ Wq_dw, const float* __restrict__ Wkv_dw,
    float* __restrict__ S, float* __restrict__ sq, float* __restrict__ sk) {
  int blk = blockIdx.x;
  int b = blk >> 9;
  int h = (blk >> 6) & 7;
  int rg = blk & 63;
  int tid = threadIdx.x;
  int wave = tid >> 6;
  int lane = tid & 63;
  int y = (rg << 2) + wave;
  bool ym = y > 0, yp = y < 255;
  const float* qb = q_pre + (size_t)b * (64 * N_PIX);
  const float* kb = kv_pre + (size_t)b * (128 * N_PIX);

  float prod[8][8], sqp[8], skp[8];
#pragma unroll
  for (int r = 0; r < 8; r++) {
    sqp[r] = 0.f; skp[r] = 0.f;
#pragma unroll
    for (int d = 0; d < 8; d++) prod[r][d] = 0.f;
  }
#pragma unroll 1
  for (int p = 0; p < 4; p++) {
    int x = lane + (p << 6);
    bool xm = x > 0, xpp = x < 255;
    int n = (y << 8) + x;
    float qd[8], kd[8];
#pragma unroll
    for (int rr = 0; rr < 8; rr++) {
      int c = h * 8 + rr;
      qd[rr] = dw3x3(qb + ((size_t)c << 16), Wq_dw + c * 9, n, ym, yp, xm, xpp);
      kd[rr] = dw3x3(kb + ((size_t)c << 16), Wkv_dw + c * 9, n, ym, yp, xm, xpp);
    }
#pragma unroll
    for (int r = 0; r < 8; r++) {
      sqp[r] = fmaf(qd[r], qd[r], sqp[r]);
      skp[r] = fmaf(kd[r], kd[r], skp[r]);
#pragma unroll
      for (int d = 0; d < 8; d++) prod[r][d] = fmaf(qd[r], kd[d], prod[r][d]);
    }
  }
  __shared__ float red[4][80];
#pragma unroll
  for (int r = 0; r < 8; r++) {
#pragma unroll
    for (int d = 0; d < 8; d++) {
      float v = wred(prod[r][d]);
      if (lane == 0) red[wave][r * 8 + d] = v;
    }
    float vq = wred(sqp[r]);
    float vk = wred(skp[r]);
    if (lane == 0) { red[wave][64 + r] = vq; red[wave][72 + r] = vk; }
  }
  __syncthreads();
  if (tid < 80) {
    float s = red[0][tid] + red[1][tid] + red[2][tid] + red[3][tid];
    if (tid < 64) atomicAdd(&S[(b * 8 + h) * 64 + tid], s);
    else if (tid < 72) atomicAdd(&sq[b * 64 + h * 8 + (tid - 64)], s);
    else atomicAdd(&sk[b * 64 + h * 8 + (tid - 72)], s);
  }
}

// ---------------- K3: softmax + M_b = Wproj * blockdiag(attn_h) ----------------
__global__ __launch_bounds__(256) void k_attn_mat(
    const float* __restrict__ S, const float* __restrict__ sq, const float* __restrict__ sk,
    const float* __restrict__ temp, const float* __restrict__ Wproj,
    float* __restrict__ Mt) {
  __shared__ float aw[4][8][8][8];
  int tid = threadIdx.x;
  {
    int b = tid >> 6, h = (tid >> 3) & 7, r = tid & 7;
    float qn = fmaxf(sqrtf(sq[b * 64 + h * 8 + r]), 1e-12f);
    float tt = temp[h];
    float lg[8];
    float mx = -1e30f;
#pragma unroll
    for (int d = 0; d < 8; d++) {
      float kn = fmaxf(sqrtf(sk[b * 64 + h * 8 + d]), 1e-12f);
      lg[d] = S[((b * 8 + h) * 8 + r) * 8 + d] / (qn * kn) * tt;
      mx = fmaxf(mx, lg[d]);
    }
    float sm = 0.f;
#pragma unroll
    for (int d = 0; d < 8; d++) { lg[d] = __expf(lg[d] - mx); sm += lg[d]; }
    float inv = 1.f / sm;
#pragma unroll
    for (int d = 0; d < 8; d++) aw[b][h][r][d] = lg[d] * inv;
  }
  __syncthreads();
  {
    int b = tid >> 6, o = tid & 63;
#pragma unroll 1
    for (int h = 0; h < 8; h++) {
#pragma unroll
      for (int d = 0; d < 8; d++) {
        float m = 0.f;
#pragma unroll
        for (int r = 0; r < 8; r++) m = fmaf(Wproj[o * 64 + h * 8 + r], aw[b][h][r][d], m);
        Mt[(size_t)(b * 64 + (h * 8 + d)) * 64 + o] = m;  // [b][dg][o]
      }
    }
  }
}

// ---------------- K4a: dwconv(v) + M-matvec + residual + LN2 -> x1 (f32), xn2 (bf16 pixel-major) ----
__global__ __launch_bounds__(256) void k_cab_out(
    const float* __restrict__ x, const float* __restrict__ kv_pre,
    const float* __restrict__ Wkv_dw, const float* __restrict__ Mt,
    const float* __restrict__ ln2w, const float* __restrict__ ln2b,
    float* __restrict__ x1, unsigned short* __restrict__ xn2b) {
  int b = blockIdx.x >> 8;
  int yy = blockIdx.x & 255;
  int xcol = threadIdx.x;
  int n = (yy << 8) + xcol;
  bool ym = yy > 0, yp = yy < 255, xm = xcol > 0, xpp = xcol < 255;
  const float* vb = kv_pre + (size_t)b * (128 * N_PIX) + ((size_t)64 << 16);
  const float* Mb = Mt + b * 4096;
  float acc[64];
#pragma unroll
  for (int o = 0; o < 64; o++) acc[o] = 0.f;
#pragma unroll 2
  for (int dg = 0; dg < 64; dg++) {
    float v = dw3x3(vb + ((size_t)dg << 16), Wkv_dw + (64 + dg) * 9, n, ym, yp, xm, xpp);
    const float* mrow = Mb + dg * 64;
#pragma unroll
    for (int o = 0; o < 64; o++) acc[o] = fmaf(mrow[o], v, acc[o]);
  }
  const float* px = x + (size_t)b * (64 * N_PIX) + n;
  float* px1 = x1 + (size_t)b * (64 * N_PIX) + n;
  float s1 = 0.f, s2 = 0.f;
#pragma unroll
  for (int c = 0; c < 64; c++) {
    float v = px[(size_t)c << 16] + acc[c];
    acc[c] = v;
    px1[(size_t)c << 16] = v;
    s1 += v;
    s2 = fmaf(v, v, s2);
  }
  float mu = s1 * 0.015625f;
  float var = fmaf(s2, 0.015625f, -mu * mu);
  float rs = rsqrtf(var + 1e-5f);
  unsigned short* pxn = xn2b + ((size_t)b << 24) + ((size_t)n << 6);
#pragma unroll
  for (int c = 0; c < 64; c += 8) {
    float t0 = fmaf((acc[c + 0] - mu) * rs, ln2w[c + 0], ln2b[c + 0]);
    float t1 = fmaf((acc[c + 1] - mu) * rs, ln2w[c + 1], ln2b[c + 1]);
    float t2 = fmaf((acc[c + 2] - mu) * rs, ln2w[c + 2], ln2b[c + 2]);
    float t3 = fmaf((acc[c + 3] - mu) * rs, ln2w[c + 3], ln2b[c + 3]);
    float t4 = fmaf((acc[c + 4] - mu) * rs, ln2w[c + 4], ln2b[c + 4]);
    float t5 = fmaf((acc[c + 5] - mu) * rs, ln2w[c + 5], ln2b[c + 5]);
    float t6 = fmaf((acc[c + 6] - mu) * rs, ln2w[c + 6], ln2b[c + 6]);
    float t7 = fmaf((acc[c + 7] - mu) * rs, ln2w[c + 7], ln2b[c + 7]);
    uint4 u;
    u.x = pk2(t0, t1); u.y = pk2(t2, t3); u.z = pk2(t4, t5); u.w = pk2(t6, t7);
    *reinterpret_cast<uint4*>(pxn + c) = u;
  }
}

// ---------------- K4b: MFMA FFN: xn2 -> W12 -> silu-gate -> W3 -> +x1 -> out ----------------
// block = 4 waves; each wave owns 32 pixels (2 M-tiles of 16). GEMM1: K=64, N=176(+176);
// GEMM2: K=192 (padded), N=64. g bounced through wave-private LDS.
__global__ __launch_bounds__(256) void k_ffn(
    const float* __restrict__ x1, const unsigned short* __restrict__ xn2b,
    const unsigned short* __restrict__ W12s, const unsigned short* __restrict__ W3s,
    float* __restrict__ outp) {
  __shared__ unsigned short g_all[4][32 * 200];  // 51.2 KB
  int b = blockIdx.x >> 9;
  int pblk = (blockIdx.x & 511) << 7;
  int w = threadIdx.x >> 6;
  int l = threadIdx.x & 63;
  int pix0 = pblk + (w << 5);
  int lrow = l & 15, lgrp = l >> 4;
  unsigned short* gl = &g_all[w][0];

  // zero-pad g cols 176..191 (K-padding for GEMM2; W3s rows there are 0 but avoid NaN*0)
  {
    unsigned int* gz = (unsigned int*)(gl + (size_t)(l & 31) * 200);
    int base = 88 + ((l >> 5) << 2);
    gz[base] = 0u; gz[base + 1] = 0u; gz[base + 2] = 0u; gz[base + 3] = 0u;
  }

  const unsigned short* xn2 = xn2b + ((size_t)b << 24);
  bf16x8 a1[2][2];
#pragma unroll
  for (int mt = 0; mt < 2; mt++)
#pragma unroll
    for (int kk = 0; kk < 2; kk++)
      a1[mt][kk] = *(const bf16x8*)(xn2 + (((size_t)(pix0 + mt * 16 + lrow)) << 6) + (kk << 5) + (lgrp << 3));

  // GEMM1 + gate
#pragma unroll 1
  for (int nt = 0; nt < 11; nt++) {
    f32x4 h1[2], h2[2];
#pragma unroll
    for (int mt = 0; mt < 2; mt++) {
      h1[mt] = (f32x4){0.f, 0.f, 0.f, 0.f};
      h2[mt] = (f32x4){0.f, 0.f, 0.f, 0.f};
    }
#pragma unroll
    for (int kk = 0; kk < 2; kk++) {
      bf16x8 b1 = *(const bf16x8*)(W12s + ((((nt << 1) + kk) << 6) + l) * 8);
      bf16x8 b2 = *(const bf16x8*)(W12s + (((((nt + 11) << 1) + kk) << 6) + l) * 8);
#pragma unroll
      for (int mt = 0; mt < 2; mt++) {
        h1[mt] = __builtin_amdgcn_mfma_f32_16x16x32_bf16(a1[mt][kk], b1, h1[mt], 0, 0, 0);
        h2[mt] = __builtin_amdgcn_mfma_f32_16x16x32_bf16(a1[mt][kk], b2, h2[mt], 0, 0, 0);
      }
    }
#pragma unroll
    for (int mt = 0; mt < 2; mt++)
#pragma unroll
      for (int r = 0; r < 4; r++) {
        float hh1 = h1[mt][r], hh2 = h2[mt][r];
        float g = hh1 * __builtin_amdgcn_rcpf(1.f + __expf(-hh1)) * hh2;
        gl[(mt * 16 + (lgrp << 2) + r) * 200 + nt * 16 + lrow] = f2bf(g);
      }
  }
  __syncthreads();  // cross-lane LDS visibility (g written by other lanes)

  // GEMM2
  f32x4 acc[2][4];
#pragma unroll
  for (int mt = 0; mt < 2; mt++)
#pragma unroll
    for (int nt2 = 0; nt2 < 4; nt2++) acc[mt][nt2] = (f32x4){0.f, 0.f, 0.f, 0.f};
#pragma unroll 1
  for (int kk = 0; kk < 6; kk++) {
    bf16x8 a2[2];
#pragma unroll
    for (int mt = 0; mt < 2; mt++)
      a2[mt] = *(const bf16x8*)(gl + (mt * 16 + lrow) * 200 + (kk << 5) + (lgrp << 3));
#pragma unroll
    for (int nt2 = 0; nt2 < 4; nt2++) {
      bf16x8 b3 = *(const bf16x8*)(W3s + (((nt2 * 6 + kk) << 6) + l) * 8);
#pragma unroll
      for (int mt = 0; mt < 2; mt++)
        acc[mt][nt2] = __builtin_amdgcn_mfma_f32_16x16x32_bf16(a2[mt], b3, acc[mt][nt2], 0, 0, 0);
    }
  }
  __syncthreads();  // all LDS reads done before overwriting with f32 out tile

  float* ol = (float*)gl;  // [32][67] f32, stride 67 (conflict-free readback)
#pragma unroll
  for (int mt = 0; mt < 2; mt++)
#pragma unroll
    for (int nt2 = 0; nt2 < 4; nt2++)
#pragma unroll
      for (int r = 0; r < 4; r++)
        ol[(mt * 16 + (lgrp << 2) + r) * 67 + nt2 * 16 + lrow] = acc[mt][nt2][r];
  __syncthreads();  // out tile visible

  // fused +x1, channel-major coalesced writeout: 2 channels x 32 pixels per iter
#pragma unroll 2
  for (int it = 0; it < 32; it++) {
    int o = (it << 1) + (l >> 5);
    int p = l & 31;
    size_t gi = (((size_t)b << 6) + (size_t)o) * N_PIX + (size_t)(pix0 + p);
    outp[gi] = x1[gi] + ol[p * 67 + o];
  }
}

extern "C" void kernel_launch(void* const* d_in, const int* in_sizes, int n_in,
                              void* d_out, int out_size, void* d_ws, size_t ws_size,
                              hipStream_t stream) {
  const float* x      = (const float*)d_in[0];
  const float* y      = (const float*)d_in[1];
  const float* ln1xw  = (const float*)d_in[2];
  const float* ln1xb  = (const float*)d_in[3];
  const float* ln1yw  = (const float*)d_in[4];
  const float* ln1yb  = (const float*)d_in[5];
  const float* ln2w   = (const float*)d_in[6];
  const float* ln2b   = (const float*)d_in[7];
  const float* Wq     = (const float*)d_in[8];
  const float* Wq_dw  = (const float*)d_in[9];
  const float* Wkv    = (const float*)d_in[10];
  const float* Wkv_dw = (const float*)d_in[11];
  const float* Wproj  = (const float*)d_in[12];
  const float* temp   = (const float*)d_in[13];
  const float* W12    = (const float*)d_in[14];
  const float* W3     = (const float*)d_in[15];
  float* out = (float*)d_out;
  float* ws = (float*)d_ws;

  float* q_pre  = ws + OFF_QPRE;
  float* kv_pre = ws + OFF_KVPRE;
  float* Sb     = ws + OFF_S;
  float* sqb    = ws + OFF_SQ;
  float* skb    = ws + OFF_SK;
  float* Mt     = ws + OFF_MT;
  float* x1     = ws + OFF_QPRE;                         // q_pre dead after k_qk_stats
  unsigned short* xn2b = (unsigned short*)(ws + OFF_KVPRE);  // k-half dead after k_qk_stats

  hipMemsetAsync(Sb, 0, 2560 * sizeof(float), stream);  // S + sq + sk contiguous
  k_prep<<<64, 256, 0, stream>>>(Wq, ln1xw, ln1xb, Wkv, ln1yw, ln1yb, W12, W3, ws);
  k_ln_conv1x1<64><<<1024, 256, 0, stream>>>(x, ws + OFF_WQT, 64, ws + OFF_BQ, ws + OFF_CQ, q_pre, 64);
  k_ln_conv1x1<64><<<1024, 256, 0, stream>>>(y, ws + OFF_WKVT, 128, ws + OFF_BKV, ws + OFF_CKV, kv_pre, 128);
  k_ln_conv1x1<64><<<1024, 256, 0, stream>>>(y, ws + OFF_WKVT + 64, 128, ws + OFF_BKV + 64, ws + OFF_CKV + 64,
                                             kv_pre + ((size_t)64 << 16), 128);
  k_qk_stats<<<2048, 256, 0, stream>>>(q_pre, kv_pre, Wq_dw, Wkv_dw, Sb, sqb, skb);
  k_attn_mat<<<1, 256, 0, stream>>>(Sb, sqb, skb, temp, Wproj, Mt);
  k_cab_out<<<1024, 256, 0, stream>>>(x, kv_pre, Wkv_dw, Mt, ln2w, ln2b, x1, xn2b);
  k_ffn<<<2048, 256, 0, stream>>>(x1, xn2b, (unsigned short*)(ws + OFF_W12S),
                                  (unsigned short*)(ws + OFF_W3S), out);
}

// Round 5
// 544.544 us; speedup vs baseline: 4.4703x; 1.8029x over previous
//
#include <hip/hip_runtime.h>

#define N_PIX 65536  // 256*256

typedef short bf16x8 __attribute__((ext_vector_type(8)));
typedef float f32x4 __attribute__((ext_vector_type(4)));

// ---------------- ws layout (float offsets) ----------------
#define OFF_QPRE   0u          // [4][64][65536] q_pre; reused as x1 after k_qk_stats
#define OFF_KVPRE  16777216u   // [4][128][65536]; k-half reused as xn2 bf16 after k_qk_stats
#define OFF_S      50331648u   // [4][8][8][8]
#define OFF_SQ     50333696u   // [4][64]
#define OFF_SK     50333952u   // [4][64]
#define OFF_MT     50334208u   // [4][64][64]  (dg-major, o contiguous)
#define OFF_WQT    50350592u   // [64][64]   Wq^T * ln1x_w
#define OFF_BQ     50354688u   // [64]
#define OFF_CQ     50354752u   // [64]
#define OFF_WKVT   50354816u   // [64][128]  Wkv^T * ln1y_w
#define OFF_BKV    50363008u   // [128]
#define OFF_CKV    50363136u   // [128]
#define OFF_W12S   50363264u   // 22528 bf16: pre-fragmented W12 for MFMA
#define OFF_W3S    50374528u   // 12288 bf16: pre-fragmented W3 for MFMA
// total 50380672 floats = 201,522,688 bytes

__device__ __forceinline__ unsigned short f2bf(float f) {
  unsigned int u = __float_as_uint(f);
  unsigned int r = (u + 0x7FFFu + ((u >> 16) & 1u)) >> 16;
  return (unsigned short)r;
}
__device__ __forceinline__ unsigned int pk2(float a, float b) {
  return (unsigned int)f2bf(a) | ((unsigned int)f2bf(b) << 16);
}
__device__ __forceinline__ float bf2f(unsigned short u) {
  return __uint_as_float(((unsigned int)u) << 16);
}

// ---- vectorized 3x3 depthwise stencil: wave owns one row, lane owns 4 px (float4) ----
__device__ __forceinline__ void dwrow_acc(float4& a, const float4 v, float l, float r,
                                          float w0, float w1, float w2) {
  a.x = fmaf(l,   w0, fmaf(v.x, w1, fmaf(v.y, w2, a.x)));
  a.y = fmaf(v.x, w0, fmaf(v.y, w1, fmaf(v.z, w2, a.y)));
  a.z = fmaf(v.y, w0, fmaf(v.z, w1, fmaf(v.w, w2, a.z)));
  a.w = fmaf(v.z, w0, fmaf(v.w, w1, fmaf(r,   w2, a.w)));
}

__device__ __forceinline__ float4 dw3x3v(const float* __restrict__ pch,
                                         const float* __restrict__ w,
                                         int nb, int lane, bool ym, bool yp) {
  float4 a = {0.f, 0.f, 0.f, 0.f};
  {
    float4 v = *reinterpret_cast<const float4*>(pch + nb);
    float l = __shfl_up(v.w, 1);   if (lane == 0) l = 0.f;
    float r = __shfl_down(v.x, 1); if (lane == 63) r = 0.f;
    dwrow_acc(a, v, l, r, w[3], w[4], w[5]);
  }
  if (ym) {
    float4 v = *reinterpret_cast<const float4*>(pch + nb - 256);
    float l = __shfl_up(v.w, 1);   if (lane == 0) l = 0.f;
    float r = __shfl_down(v.x, 1); if (lane == 63) r = 0.f;
    dwrow_acc(a, v, l, r, w[0], w[1], w[2]);
  }
  if (yp) {
    float4 v = *reinterpret_cast<const float4*>(pch + nb + 256);
    float l = __shfl_up(v.w, 1);   if (lane == 0) l = 0.f;
    float r = __shfl_down(v.x, 1); if (lane == 63) r = 0.f;
    dwrow_acc(a, v, l, r, w[6], w[7], w[8]);
  }
  return a;
}

__device__ __forceinline__ float dot4(const float4 a, const float4 b) {
  return fmaf(a.x, b.x, fmaf(a.y, b.y, fmaf(a.z, b.z, a.w * b.w)));
}

__device__ __forceinline__ float wred(float v) {
#pragma unroll
  for (int m = 32; m >= 1; m >>= 1) v += __shfl_xor(v, m, 64);
  return v;
}

// ---------------- K0: weight prep (parallel) ----------------
__global__ __launch_bounds__(256) void k_prep(
    const float* __restrict__ Wq, const float* __restrict__ ln1xw, const float* __restrict__ ln1xb,
    const float* __restrict__ Wkv, const float* __restrict__ ln1yw, const float* __restrict__ ln1yb,
    const float* __restrict__ W12, const float* __restrict__ W3, float* __restrict__ ws) {
  int gtid = blockIdx.x * 256 + threadIdx.x;
  int gstride = gridDim.x * 256;
  float* Wqt = ws + OFF_WQT; float* Bq = ws + OFF_BQ; float* Cq = ws + OFF_CQ;
  float* Wkvt = ws + OFF_WKVT; float* Bkv = ws + OFF_BKV; float* Ckv = ws + OFF_CKV;
  unsigned short* W12s = (unsigned short*)(ws + OFF_W12S);
  unsigned short* W3s = (unsigned short*)(ws + OFF_W3S);
  for (int i = gtid; i < 4096; i += gstride) {
    int c = i >> 6, o = i & 63;
    Wqt[c * 64 + o] = Wq[o * 64 + c] * ln1xw[c];
  }
  for (int i = gtid; i < 8192; i += gstride) {
    int c = i >> 7, o = i & 127;
    Wkvt[c * 128 + o] = Wkv[o * 64 + c] * ln1yw[c];
  }
  for (int i = gtid; i < 22528; i += gstride) {
    int e = i & 7, lane = (i >> 3) & 63, fi = i >> 9;
    int kk = fi & 1, ntg = fi >> 1;
    int half = ntg / 11, ntl = ntg % 11;
    int j = ntl * 16 + (lane & 15);
    int k = kk * 32 + ((lane >> 4) << 3) + e;
    float v = (j < 170) ? W12[(half * 170 + j) * 64 + k] : 0.f;
    W12s[i] = f2bf(v);
  }
  for (int i = gtid; i < 12288; i += gstride) {
    int e = i & 7, lane = (i >> 3) & 63, fi = i >> 9;
    int kk = fi % 6, nt2 = fi / 6;
    int o = nt2 * 16 + (lane & 15);
    int k = kk * 32 + ((lane >> 4) << 3) + e;
    float v = (k < 170) ? W3[o * 170 + k] : 0.f;
    W3s[i] = f2bf(v);
  }
  if (gtid < 64) {
    float bq = 0.f, cq = 0.f;
    for (int c = 0; c < 64; c++) {
      bq = fmaf(Wq[gtid * 64 + c], ln1xw[c], bq);
      cq = fmaf(Wq[gtid * 64 + c], ln1xb[c], cq);
    }
    Bq[gtid] = bq; Cq[gtid] = cq;
  }
  if (gtid >= 64 && gtid < 192) {
    int t = gtid - 64;
    float bk = 0.f, ck = 0.f;
    for (int c = 0; c < 64; c++) {
      bk = fmaf(Wkv[t * 64 + c], ln1yw[c], bk);
      ck = fmaf(Wkv[t * 64 + c], ln1yb[c], ck);
    }
    Bkv[t] = bk; Ckv[t] = ck;
  }
}

// ---------------- K1: fused LN + 1x1 conv (single pass) ----------------
template <int NOUT>
__global__ __launch_bounds__(256) void k_ln_conv1x1(
    const float* __restrict__ in, const float* __restrict__ Wt, int wstride,
    const float* __restrict__ Bv, const float* __restrict__ Cv,
    float* __restrict__ outp, int bstride) {
  int b = blockIdx.x >> 8;
  int n = ((blockIdx.x & 255) << 8) + threadIdx.x;
  const float* px = in + (size_t)b * (64 * N_PIX) + n;
  float acc[NOUT];
#pragma unroll
  for (int o = 0; o < NOUT; o++) acc[o] = 0.f;
  float s1 = 0.f, s2 = 0.f;
#pragma unroll 2
  for (int c = 0; c < 64; c++) {
    float xv = px[(size_t)c << 16];
    s1 += xv;
    s2 = fmaf(xv, xv, s2);
    const float* wrow = Wt + c * wstride;
#pragma unroll
    for (int o = 0; o < NOUT; o++) acc[o] = fmaf(wrow[o], xv, acc[o]);
  }
  float mu = s1 * 0.015625f;
  float var = fmaf(s2, 0.015625f, -mu * mu);
  float rs = rsqrtf(var + 1e-5f);
  float rm = rs * mu;
  float* po = outp + (size_t)b * ((size_t)bstride * N_PIX) + n;
#pragma unroll
  for (int o = 0; o < NOUT; o++) {
    po[(size_t)o << 16] = fmaf(rs, acc[o], fmaf(-rm, Bv[o], Cv[o]));
  }
}

// ---------------- K2: qk stats (vectorized stencil) ----------------
// grid: 4b x 8h x 64 rowgroups = 2048 blocks; wave = one row, lane = 4 px (float4)
__global__ __launch_bounds__(256) void k_qk_stats(
    const float* __restrict__ q_pre, const float* __restrict__ kv_pre,
    const float* __restrict__ Wq_dw, const float* __restrict__ Wkv_dw,
    float* __restrict__ S, float* __restrict__ sq, float* __restrict__ sk) {
  int blk = blockIdx.x;
  int b = blk >> 9;
  int h = (blk >> 6) & 7;
  int rg = blk & 63;
  int tid = threadIdx.x;
  int wave = tid >> 6;
  int lane = tid & 63;
  int y = (rg << 2) + wave;
  bool ym = y > 0, yp = y < 255;
  int nb = (y << 8) + (lane << 2);
  const float* qb = q_pre + (size_t)b * (64 * N_PIX);
  const float* kb = kv_pre + (size_t)b * (128 * N_PIX);

  float4 qd[8];
  float sqp[8], skp[8], prod[8][8];
#pragma unroll
  for (int r = 0; r < 8; r++) {
    int c = (h << 3) + r;
    qd[r] = dw3x3v(qb + ((size_t)c << 16), Wq_dw + c * 9, nb, lane, ym, yp);
    sqp[r] = dot4(qd[r], qd[r]);
  }
#pragma unroll
  for (int d = 0; d < 8; d++) {
    int c = (h << 3) + d;
    float4 kdv = dw3x3v(kb + ((size_t)c << 16), Wkv_dw + c * 9, nb, lane, ym, yp);
    skp[d] = dot4(kdv, kdv);
#pragma unroll
    for (int r = 0; r < 8; r++) prod[r][d] = dot4(qd[r], kdv);
  }

  __shared__ float red[4][80];
#pragma unroll
  for (int r = 0; r < 8; r++) {
#pragma unroll
    for (int d = 0; d < 8; d++) {
      float v = wred(prod[r][d]);
      if (lane == 0) red[wave][r * 8 + d] = v;
    }
    float vq = wred(sqp[r]);
    float vk = wred(skp[r]);
    if (lane == 0) { red[wave][64 + r] = vq; red[wave][72 + r] = vk; }
  }
  __syncthreads();
  if (tid < 80) {
    float s = red[0][tid] + red[1][tid] + red[2][tid] + red[3][tid];
    if (tid < 64) atomicAdd(&S[(b * 8 + h) * 64 + tid], s);
    else if (tid < 72) atomicAdd(&sq[b * 64 + h * 8 + (tid - 64)], s);
    else atomicAdd(&sk[b * 64 + h * 8 + (tid - 72)], s);
  }
}

// ---------------- K3: softmax + M_b = Wproj * blockdiag(attn_h) ----------------
__global__ __launch_bounds__(256) void k_attn_mat(
    const float* __restrict__ S, const float* __restrict__ sq, const float* __restrict__ sk,
    const float* __restrict__ temp, const float* __restrict__ Wproj,
    float* __restrict__ Mt) {
  __shared__ float aw[4][8][8][8];
  int tid = threadIdx.x;
  {
    int b = tid >> 6, h = (tid >> 3) & 7, r = tid & 7;
    float qn = fmaxf(sqrtf(sq[b * 64 + h * 8 + r]), 1e-12f);
    float tt = temp[h];
    float lg[8];
    float mx = -1e30f;
#pragma unroll
    for (int d = 0; d < 8; d++) {
      float kn = fmaxf(sqrtf(sk[b * 64 + h * 8 + d]), 1e-12f);
      lg[d] = S[((b * 8 + h) * 8 + r) * 8 + d] / (qn * kn) * tt;
      mx = fmaxf(mx, lg[d]);
    }
    float sm = 0.f;
#pragma unroll
    for (int d = 0; d < 8; d++) { lg[d] = __expf(lg[d] - mx); sm += lg[d]; }
    float inv = 1.f / sm;
#pragma unroll
    for (int d = 0; d < 8; d++) aw[b][h][r][d] = lg[d] * inv;
  }
  __syncthreads();
  {
    int b = tid >> 6, o = tid & 63;
#pragma unroll 1
    for (int h = 0; h < 8; h++) {
#pragma unroll
      for (int d = 0; d < 8; d++) {
        float m = 0.f;
#pragma unroll
        for (int r = 0; r < 8; r++) m = fmaf(Wproj[o * 64 + h * 8 + r], aw[b][h][r][d], m);
        Mt[(size_t)(b * 64 + (h * 8 + d)) * 64 + o] = m;  // [b][dg][o]
      }
    }
  }
}

// ---------------- K4a: dwconv(v) via LDS + M-matvec + residual + LN2 ----------------
// grid: 4b x 256 rows = 1024 blocks. Phase A: wave w dwconvs v-channels [16w,16w+16)
// for the whole row -> bf16 LDS [64][256]. Phase B: thread = pixel, M-matvec + LN2.
__global__ __launch_bounds__(256) void k_cab_out(
    const float* __restrict__ x, const float* __restrict__ kv_pre,
    const float* __restrict__ Wkv_dw, const float* __restrict__ Mt,
    const float* __restrict__ ln2w, const float* __restrict__ ln2b,
    float* __restrict__ x1, unsigned short* __restrict__ xn2b) {
  __shared__ unsigned short vds[64][256];  // 32 KB
  int b = blockIdx.x >> 8;
  int y = blockIdx.x & 255;
  int tid = threadIdx.x;
  int wave = tid >> 6, lane = tid & 63;
  bool ym = y > 0, yp = y < 255;
  int nb = (y << 8) + (lane << 2);
  const float* vb = kv_pre + (size_t)b * (128 * N_PIX) + ((size_t)64 << 16);

  // Phase A: 16 v-channel dwconvs per wave, full row, bf16 -> LDS
#pragma unroll 2
  for (int i = 0; i < 16; i++) {
    int dg = (wave << 4) + i;
    float4 vd = dw3x3v(vb + ((size_t)dg << 16), Wkv_dw + (64 + dg) * 9, nb, lane, ym, yp);
    uint2 u;
    u.x = pk2(vd.x, vd.y);
    u.y = pk2(vd.z, vd.w);
    *reinterpret_cast<uint2*>(&vds[dg][lane << 2]) = u;
  }
  __syncthreads();

  // Phase B: thread per pixel
  int n = (y << 8) + tid;
  const float* Mb = Mt + b * 4096;
  float acc[64];
#pragma unroll
  for (int o = 0; o < 64; o++) acc[o] = 0.f;
#pragma unroll 2
  for (int dg = 0; dg < 64; dg++) {
    float v = bf2f(vds[dg][tid]);
    const float* mrow = Mb + dg * 64;
#pragma unroll
    for (int o = 0; o < 64; o++) acc[o] = fmaf(mrow[o], v, acc[o]);
  }
  const float* px = x + (size_t)b * (64 * N_PIX) + n;
  float* px1 = x1 + (size_t)b * (64 * N_PIX) + n;
  float s1 = 0.f, s2 = 0.f;
#pragma unroll
  for (int c = 0; c < 64; c++) {
    float v = px[(size_t)c << 16] + acc[c];
    acc[c] = v;
    px1[(size_t)c << 16] = v;
    s1 += v;
    s2 = fmaf(v, v, s2);
  }
  float mu = s1 * 0.015625f;
  float var = fmaf(s2, 0.015625f, -mu * mu);
  float rs = rsqrtf(var + 1e-5f);
  unsigned short* pxn = xn2b + ((size_t)b << 24) + ((size_t)n << 6);
#pragma unroll
  for (int c = 0; c < 64; c += 8) {
    float t0 = fmaf((acc[c + 0] - mu) * rs, ln2w[c + 0], ln2b[c + 0]);
    float t1 = fmaf((acc[c + 1] - mu) * rs, ln2w[c + 1], ln2b[c + 1]);
    float t2 = fmaf((acc[c + 2] - mu) * rs, ln2w[c + 2], ln2b[c + 2]);
    float t3 = fmaf((acc[c + 3] - mu) * rs, ln2w[c + 3], ln2b[c + 3]);
    float t4 = fmaf((acc[c + 4] - mu) * rs, ln2w[c + 4], ln2b[c + 4]);
    float t5 = fmaf((acc[c + 5] - mu) * rs, ln2w[c + 5], ln2b[c + 5]);
    float t6 = fmaf((acc[c + 6] - mu) * rs, ln2w[c + 6], ln2b[c + 6]);
    float t7 = fmaf((acc[c + 7] - mu) * rs, ln2w[c + 7], ln2b[c + 7]);
    uint4 u;
    u.x = pk2(t0, t1); u.y = pk2(t2, t3); u.z = pk2(t4, t5); u.w = pk2(t6, t7);
    *reinterpret_cast<uint4*>(pxn + c) = u;
  }
}

// ---------------- K4b: MFMA FFN: xn2 -> W12 -> silu-gate -> W3 -> +x1 -> out ----------------
__global__ __launch_bounds__(256) void k_ffn(
    const float* __restrict__ x1, const unsigned short* __restrict__ xn2b,
    const unsigned short* __restrict__ W12s, const unsigned short* __restrict__ W3s,
    float* __restrict__ outp) {
  __shared__ unsigned short g_all[4][32 * 200];  // 51.2 KB
  int b = blockIdx.x >> 9;
  int pblk = (blockIdx.x & 511) << 7;
  int w = threadIdx.x >> 6;
  int l = threadIdx.x & 63;
  int pix0 = pblk + (w << 5);
  int lrow = l & 15, lgrp = l >> 4;
  unsigned short* gl = &g_all[w][0];

  {
    unsigned int* gz = (unsigned int*)(gl + (size_t)(l & 31) * 200);
    int base = 88 + ((l >> 5) << 2);
    gz[base] = 0u; gz[base + 1] = 0u; gz[base + 2] = 0u; gz[base + 3] = 0u;
  }

  const unsigned short* xn2 = xn2b + ((size_t)b << 24);
  bf16x8 a1[2][2];
#pragma unroll
  for (int mt = 0; mt < 2; mt++)
#pragma unroll
    for (int kk = 0; kk < 2; kk++)
      a1[mt][kk] = *(const bf16x8*)(xn2 + (((size_t)(pix0 + mt * 16 + lrow)) << 6) + (kk << 5) + (lgrp << 3));

#pragma unroll 1
  for (int nt = 0; nt < 11; nt++) {
    f32x4 h1[2], h2[2];
#pragma unroll
    for (int mt = 0; mt < 2; mt++) {
      h1[mt] = (f32x4){0.f, 0.f, 0.f, 0.f};
      h2[mt] = (f32x4){0.f, 0.f, 0.f, 0.f};
    }
#pragma unroll
    for (int kk = 0; kk < 2; kk++) {
      bf16x8 b1 = *(const bf16x8*)(W12s + ((((nt << 1) + kk) << 6) + l) * 8);
      bf16x8 b2 = *(const bf16x8*)(W12s + (((((nt + 11) << 1) + kk) << 6) + l) * 8);
#pragma unroll
      for (int mt = 0; mt < 2; mt++) {
        h1[mt] = __builtin_amdgcn_mfma_f32_16x16x32_bf16(a1[mt][kk], b1, h1[mt], 0, 0, 0);
        h2[mt] = __builtin_amdgcn_mfma_f32_16x16x32_bf16(a1[mt][kk], b2, h2[mt], 0, 0, 0);
      }
    }
#pragma unroll
    for (int mt = 0; mt < 2; mt++)
#pragma unroll
      for (int r = 0; r < 4; r++) {
        float hh1 = h1[mt][r], hh2 = h2[mt][r];
        float g = hh1 * __builtin_amdgcn_rcpf(1.f + __expf(-hh1)) * hh2;
        gl[(mt * 16 + (lgrp << 2) + r) * 200 + nt * 16 + lrow] = f2bf(g);
      }
  }
  __syncthreads();

  f32x4 acc[2][4];
#pragma unroll
  for (int mt = 0; mt < 2; mt++)
#pragma unroll
    for (int nt2 = 0; nt2 < 4; nt2++) acc[mt][nt2] = (f32x4){0.f, 0.f, 0.f, 0.f};
#pragma unroll 1
  for (int kk = 0; kk < 6; kk++) {
    bf16x8 a2[2];
#pragma unroll
    for (int mt = 0; mt < 2; mt++)
      a2[mt] = *(const bf16x8*)(gl + (mt * 16 + lrow) * 200 + (kk << 5) + (lgrp << 3));
#pragma unroll
    for (int nt2 = 0; nt2 < 4; nt2++) {
      bf16x8 b3 = *(const bf16x8*)(W3s + (((nt2 * 6 + kk) << 6) + l) * 8);
#pragma unroll
      for (int mt = 0; mt < 2; mt++)
        acc[mt][nt2] = __builtin_amdgcn_mfma_f32_16x16x32_bf16(a2[mt], b3, acc[mt][nt2], 0, 0, 0);
    }
  }
  __syncthreads();

  float* ol = (float*)gl;  // [32][67] f32
#pragma unroll
  for (int mt = 0; mt < 2; mt++)
#pragma unroll
    for (int nt2 = 0; nt2 < 4; nt2++)
#pragma unroll
      for (int r = 0; r < 4; r++)
        ol[(mt * 16 + (lgrp << 2) + r) * 67 + nt2 * 16 + lrow] = acc[mt][nt2][r];
  __syncthreads();

#pragma unroll 2
  for (int it = 0; it < 32; it++) {
    int o = (it << 1) + (l >> 5);
    int p = l & 31;
    size_t gi = (((size_t)b << 6) + (size_t)o) * N_PIX + (size_t)(pix0 + p);
    outp[gi] = x1[gi] + ol[p * 67 + o];
  }
}

extern "C" void kernel_launch(void* const* d_in, const int* in_sizes, int n_in,
                              void* d_out, int out_size, void* d_ws, size_t ws_size,
                              hipStream_t stream) {
  const float* x      = (const float*)d_in[0];
  const float* y      = (const float*)d_in[1];
  const float* ln1xw  = (const float*)d_in[2];
  const float* ln1xb  = (const float*)d_in[3];
  const float* ln1yw  = (const float*)d_in[4];
  const float* ln1yb  = (const float*)d_in[5];
  const float* ln2w   = (const float*)d_in[6];
  const float* ln2b   = (const float*)d_in[7];
  const float* Wq     = (const float*)d_in[8];
  const float* Wq_dw  = (const float*)d_in[9];
  const float* Wkv    = (const float*)d_in[10];
  const float* Wkv_dw = (const float*)d_in[11];
  const float* Wproj  = (const float*)d_in[12];
  const float* temp   = (const float*)d_in[13];
  const float* W12    = (const float*)d_in[14];
  const float* W3     = (const float*)d_in[15];
  float* out = (float*)d_out;
  float* ws = (float*)d_ws;

  float* q_pre  = ws + OFF_QPRE;
  float* kv_pre = ws + OFF_KVPRE;
  float* Sb     = ws + OFF_S;
  float* sqb    = ws + OFF_SQ;
  float* skb    = ws + OFF_SK;
  float* Mt     = ws + OFF_MT;
  float* x1     = ws + OFF_QPRE;                             // q_pre dead after k_qk_stats
  unsigned short* xn2b = (unsigned short*)(ws + OFF_KVPRE);  // k-half dead after k_qk_stats

  hipMemsetAsync(Sb, 0, 2560 * sizeof(float), stream);  // S + sq + sk contiguous
  k_prep<<<64, 256, 0, stream>>>(Wq, ln1xw, ln1xb, Wkv, ln1yw, ln1yb, W12, W3, ws);
  k_ln_conv1x1<64><<<1024, 256, 0, stream>>>(x, ws + OFF_WQT, 64, ws + OFF_BQ, ws + OFF_CQ, q_pre, 64);
  k_ln_conv1x1<64><<<1024, 256, 0, stream>>>(y, ws + OFF_WKVT, 128, ws + OFF_BKV, ws + OFF_CKV, kv_pre, 128);
  k_ln_conv1x1<64><<<1024, 256, 0, stream>>>(y, ws + OFF_WKVT + 64, 128, ws + OFF_BKV + 64, ws + OFF_CKV + 64,
                                             kv_pre + ((size_t)64 << 16), 128);
  k_qk_stats<<<2048, 256, 0, stream>>>(q_pre, kv_pre, Wq_dw, Wkv_dw, Sb, sqb, skb);
  k_attn_mat<<<1, 256, 0, stream>>>(Sb, sqb, skb, temp, Wproj, Mt);
  k_cab_out<<<1024, 256, 0, stream>>>(x, kv_pre, Wkv_dw, Mt, ln2w, ln2b, x1, xn2b);
  k_ffn<<<2048, 256, 0, stream>>>(x1, xn2b, (unsigned short*)(ws + OFF_W12S),
                                  (unsigned short*)(ws + OFF_W3S), out);
}

// Round 6
// 544.366 us; speedup vs baseline: 4.4718x; 1.0003x over previous
//
#include <hip/hip_runtime.h>

#define N_PIX 65536  // 256*256

typedef short bf16x8 __attribute__((ext_vector_type(8)));
typedef float f32x4 __attribute__((ext_vector_type(4)));

// ---------------- ws layout (float offsets) ----------------
#define OFF_QPRE   0u          // [4][64][65536] q_pre; reused as x1 after k_qk_stats
#define OFF_KVPRE  16777216u   // [4][128][65536]; k-half reused as xn2 bf16 after k_qk_stats
#define OFF_S      50331648u   // [4][8][8][8]
#define OFF_SQ     50333696u   // [4][64]
#define OFF_SK     50333952u   // [4][64]
#define OFF_MT     50334208u   // [4][64][64]  (dg-major, o contiguous)
#define OFF_WQT    50350592u   // [64][64]   Wq^T * ln1x_w
#define OFF_BQ     50354688u   // [64]
#define OFF_CQ     50354752u   // [64]
#define OFF_WKVT   50354816u   // [64][128]  Wkv^T * ln1y_w
#define OFF_BKV    50363008u   // [128]
#define OFF_CKV    50363136u   // [128]
#define OFF_W12S   50363264u   // 22528 bf16: pre-fragmented W12 for MFMA
#define OFF_W3S    50374528u   // 12288 bf16: pre-fragmented W3 for MFMA
// total 50380672 floats = 201,522,688 bytes

__device__ __forceinline__ unsigned short f2bf(float f) {
  unsigned int u = __float_as_uint(f);
  unsigned int r = (u + 0x7FFFu + ((u >> 16) & 1u)) >> 16;
  return (unsigned short)r;
}
__device__ __forceinline__ unsigned int pk2(float a, float b) {
  return (unsigned int)f2bf(a) | ((unsigned int)f2bf(b) << 16);
}
__device__ __forceinline__ float bf2f(unsigned short u) {
  return __uint_as_float(((unsigned int)u) << 16);
}

// ---- vectorized 3x3 depthwise stencil: wave owns one row, lane owns 4 px (float4) ----
__device__ __forceinline__ void dwrow_acc(float4& a, const float4 v, float l, float r,
                                          float w0, float w1, float w2) {
  a.x = fmaf(l,   w0, fmaf(v.x, w1, fmaf(v.y, w2, a.x)));
  a.y = fmaf(v.x, w0, fmaf(v.y, w1, fmaf(v.z, w2, a.y)));
  a.z = fmaf(v.y, w0, fmaf(v.z, w1, fmaf(v.w, w2, a.z)));
  a.w = fmaf(v.z, w0, fmaf(v.w, w1, fmaf(r,   w2, a.w)));
}

__device__ __forceinline__ float4 dw3x3v(const float* __restrict__ pch,
                                         const float* __restrict__ w,
                                         int nb, int lane, bool ym, bool yp) {
  float4 a = {0.f, 0.f, 0.f, 0.f};
  {
    float4 v = *reinterpret_cast<const float4*>(pch + nb);
    float l = __shfl_up(v.w, 1);   if (lane == 0) l = 0.f;
    float r = __shfl_down(v.x, 1); if (lane == 63) r = 0.f;
    dwrow_acc(a, v, l, r, w[3], w[4], w[5]);
  }
  if (ym) {
    float4 v = *reinterpret_cast<const float4*>(pch + nb - 256);
    float l = __shfl_up(v.w, 1);   if (lane == 0) l = 0.f;
    float r = __shfl_down(v.x, 1); if (lane == 63) r = 0.f;
    dwrow_acc(a, v, l, r, w[0], w[1], w[2]);
  }
  if (yp) {
    float4 v = *reinterpret_cast<const float4*>(pch + nb + 256);
    float l = __shfl_up(v.w, 1);   if (lane == 0) l = 0.f;
    float r = __shfl_down(v.x, 1); if (lane == 63) r = 0.f;
    dwrow_acc(a, v, l, r, w[6], w[7], w[8]);
  }
  return a;
}

__device__ __forceinline__ float dot4(const float4 a, const float4 b) {
  return fmaf(a.x, b.x, fmaf(a.y, b.y, fmaf(a.z, b.z, a.w * b.w)));
}

__device__ __forceinline__ float wred(float v) {
#pragma unroll
  for (int m = 32; m >= 1; m >>= 1) v += __shfl_xor(v, m, 64);
  return v;
}

// ---------------- K0: weight prep (parallel) + zero the stat accumulators ----------------
__global__ __launch_bounds__(256) void k_prep(
    const float* __restrict__ Wq, const float* __restrict__ ln1xw, const float* __restrict__ ln1xb,
    const float* __restrict__ Wkv, const float* __restrict__ ln1yw, const float* __restrict__ ln1yb,
    const float* __restrict__ W12, const float* __restrict__ W3, float* __restrict__ ws) {
  int gtid = blockIdx.x * 256 + threadIdx.x;
  int gstride = gridDim.x * 256;
  float* Wqt = ws + OFF_WQT; float* Bq = ws + OFF_BQ; float* Cq = ws + OFF_CQ;
  float* Wkvt = ws + OFF_WKVT; float* Bkv = ws + OFF_BKV; float* Ckv = ws + OFF_CKV;
  unsigned short* W12s = (unsigned short*)(ws + OFF_W12S);
  unsigned short* W3s = (unsigned short*)(ws + OFF_W3S);
  for (int i = gtid; i < 2560; i += gstride) ws[OFF_S + i] = 0.f;  // S + sq + sk
  for (int i = gtid; i < 4096; i += gstride) {
    int c = i >> 6, o = i & 63;
    Wqt[c * 64 + o] = Wq[o * 64 + c] * ln1xw[c];
  }
  for (int i = gtid; i < 8192; i += gstride) {
    int c = i >> 7, o = i & 127;
    Wkvt[c * 128 + o] = Wkv[o * 64 + c] * ln1yw[c];
  }
  for (int i = gtid; i < 22528; i += gstride) {
    int e = i & 7, lane = (i >> 3) & 63, fi = i >> 9;
    int kk = fi & 1, ntg = fi >> 1;
    int half = ntg / 11, ntl = ntg % 11;
    int j = ntl * 16 + (lane & 15);
    int k = kk * 32 + ((lane >> 4) << 3) + e;
    float v = (j < 170) ? W12[(half * 170 + j) * 64 + k] : 0.f;
    W12s[i] = f2bf(v);
  }
  for (int i = gtid; i < 12288; i += gstride) {
    int e = i & 7, lane = (i >> 3) & 63, fi = i >> 9;
    int kk = fi % 6, nt2 = fi / 6;
    int o = nt2 * 16 + (lane & 15);
    int k = kk * 32 + ((lane >> 4) << 3) + e;
    float v = (k < 170) ? W3[o * 170 + k] : 0.f;
    W3s[i] = f2bf(v);
  }
  if (gtid < 64) {
    float bq = 0.f, cq = 0.f;
    for (int c = 0; c < 64; c++) {
      bq = fmaf(Wq[gtid * 64 + c], ln1xw[c], bq);
      cq = fmaf(Wq[gtid * 64 + c], ln1xb[c], cq);
    }
    Bq[gtid] = bq; Cq[gtid] = cq;
  }
  if (gtid >= 64 && gtid < 192) {
    int t = gtid - 64;
    float bk = 0.f, ck = 0.f;
    for (int c = 0; c < 64; c++) {
      bk = fmaf(Wkv[t * 64 + c], ln1yw[c], bk);
      ck = fmaf(Wkv[t * 64 + c], ln1yb[c], ck);
    }
    Bkv[t] = bk; Ckv[t] = ck;
  }
}

// ---------------- K1a: fused LN + 1x1 conv, 64 outputs (q path) ----------------
__global__ __launch_bounds__(256) void k_ln_conv_q(
    const float* __restrict__ in, const float* __restrict__ Wt,
    const float* __restrict__ Bv, const float* __restrict__ Cv,
    float* __restrict__ outp) {
  int b = blockIdx.x >> 8;
  int n = ((blockIdx.x & 255) << 8) + threadIdx.x;
  const float* px = in + (size_t)b * (64 * N_PIX) + n;
  float acc[64];
#pragma unroll
  for (int o = 0; o < 64; o++) acc[o] = 0.f;
  float s1 = 0.f, s2 = 0.f;
#pragma unroll 2
  for (int c = 0; c < 64; c++) {
    float xv = px[(size_t)c << 16];
    s1 += xv;
    s2 = fmaf(xv, xv, s2);
    const float* wrow = Wt + c * 64;
#pragma unroll
    for (int o = 0; o < 64; o++) acc[o] = fmaf(wrow[o], xv, acc[o]);
  }
  float mu = s1 * 0.015625f;
  float var = fmaf(s2, 0.015625f, -mu * mu);
  float rs = rsqrtf(var + 1e-5f);
  float rm = rs * mu;
  float* po = outp + (size_t)b * (64 * N_PIX) + n;
#pragma unroll
  for (int o = 0; o < 64; o++) {
    po[(size_t)o << 16] = fmaf(rs, acc[o], fmaf(-rm, Bv[o], Cv[o]));
  }
}

// ---------------- K1b: fused LN + 1x1 conv, 128 outputs (kv path, single y pass) ----------------
// acc[128] ~ 150 VGPR; (256,3) caps at 170 -> no spill, 3 waves/SIMD.
__global__ __launch_bounds__(256, 3) void k_ln_conv_kv(
    const float* __restrict__ in, const float* __restrict__ Wt,
    const float* __restrict__ Bv, const float* __restrict__ Cv,
    float* __restrict__ outp) {
  int b = blockIdx.x >> 8;
  int n = ((blockIdx.x & 255) << 8) + threadIdx.x;
  const float* px = in + (size_t)b * (64 * N_PIX) + n;
  float acc[128];
#pragma unroll
  for (int o = 0; o < 128; o++) acc[o] = 0.f;
  float s1 = 0.f, s2 = 0.f;
#pragma unroll 1
  for (int c = 0; c < 64; c++) {
    float xv = px[(size_t)c << 16];
    s1 += xv;
    s2 = fmaf(xv, xv, s2);
    const float* wrow = Wt + c * 128;
#pragma unroll
    for (int o = 0; o < 128; o++) acc[o] = fmaf(wrow[o], xv, acc[o]);
  }
  float mu = s1 * 0.015625f;
  float var = fmaf(s2, 0.015625f, -mu * mu);
  float rs = rsqrtf(var + 1e-5f);
  float rm = rs * mu;
  float* po = outp + (size_t)b * (128 * N_PIX) + n;
#pragma unroll
  for (int o = 0; o < 128; o++) {
    po[(size_t)o << 16] = fmaf(rs, acc[o], fmaf(-rm, Bv[o], Cv[o]));
  }
}

// ---------------- K2: qk stats (vectorized stencil) ----------------
// grid: 4b x 8h x 64 rowgroups = 2048 blocks; wave = one row, lane = 4 px (float4)
__global__ __launch_bounds__(256) void k_qk_stats(
    const float* __restrict__ q_pre, const float* __restrict__ kv_pre,
    const float* __restrict__ Wq_dw, const float* __restrict__ Wkv_dw,
    float* __restrict__ S, float* __restrict__ sq, float* __restrict__ sk) {
  int blk = blockIdx.x;
  int b = blk >> 9;
  int h = (blk >> 6) & 7;
  int rg = blk & 63;
  int tid = threadIdx.x;
  int wave = tid >> 6;
  int lane = tid & 63;
  int y = (rg << 2) + wave;
  bool ym = y > 0, yp = y < 255;
  int nb = (y << 8) + (lane << 2);
  const float* qb = q_pre + (size_t)b * (64 * N_PIX);
  const float* kb = kv_pre + (size_t)b * (128 * N_PIX);

  float4 qd[8];
  float sqp[8], skp[8], prod[8][8];
#pragma unroll
  for (int r = 0; r < 8; r++) {
    int c = (h << 3) + r;
    qd[r] = dw3x3v(qb + ((size_t)c << 16), Wq_dw + c * 9, nb, lane, ym, yp);
    sqp[r] = dot4(qd[r], qd[r]);
  }
#pragma unroll
  for (int d = 0; d < 8; d++) {
    int c = (h << 3) + d;
    float4 kdv = dw3x3v(kb + ((size_t)c << 16), Wkv_dw + c * 9, nb, lane, ym, yp);
    skp[d] = dot4(kdv, kdv);
#pragma unroll
    for (int r = 0; r < 8; r++) prod[r][d] = dot4(qd[r], kdv);
  }

  __shared__ float red[4][80];
#pragma unroll
  for (int r = 0; r < 8; r++) {
#pragma unroll
    for (int d = 0; d < 8; d++) {
      float v = wred(prod[r][d]);
      if (lane == 0) red[wave][r * 8 + d] = v;
    }
    float vq = wred(sqp[r]);
    float vk = wred(skp[r]);
    if (lane == 0) { red[wave][64 + r] = vq; red[wave][72 + r] = vk; }
  }
  __syncthreads();
  if (tid < 80) {
    float s = red[0][tid] + red[1][tid] + red[2][tid] + red[3][tid];
    if (tid < 64) atomicAdd(&S[(b * 8 + h) * 64 + tid], s);
    else if (tid < 72) atomicAdd(&sq[b * 64 + h * 8 + (tid - 64)], s);
    else atomicAdd(&sk[b * 64 + h * 8 + (tid - 72)], s);
  }
}

// ---------------- K3: softmax + M_b = Wproj * blockdiag(attn_h) ----------------
__global__ __launch_bounds__(256) void k_attn_mat(
    const float* __restrict__ S, const float* __restrict__ sq, const float* __restrict__ sk,
    const float* __restrict__ temp, const float* __restrict__ Wproj,
    float* __restrict__ Mt) {
  __shared__ float aw[4][8][8][8];
  int tid = threadIdx.x;
  {
    int b = tid >> 6, h = (tid >> 3) & 7, r = tid & 7;
    float qn = fmaxf(sqrtf(sq[b * 64 + h * 8 + r]), 1e-12f);
    float tt = temp[h];
    float lg[8];
    float mx = -1e30f;
#pragma unroll
    for (int d = 0; d < 8; d++) {
      float kn = fmaxf(sqrtf(sk[b * 64 + h * 8 + d]), 1e-12f);
      lg[d] = S[((b * 8 + h) * 8 + r) * 8 + d] / (qn * kn) * tt;
      mx = fmaxf(mx, lg[d]);
    }
    float sm = 0.f;
#pragma unroll
    for (int d = 0; d < 8; d++) { lg[d] = __expf(lg[d] - mx); sm += lg[d]; }
    float inv = 1.f / sm;
#pragma unroll
    for (int d = 0; d < 8; d++) aw[b][h][r][d] = lg[d] * inv;
  }
  __syncthreads();
  {
    int b = tid >> 6, o = tid & 63;
#pragma unroll 1
    for (int h = 0; h < 8; h++) {
#pragma unroll
      for (int d = 0; d < 8; d++) {
        float m = 0.f;
#pragma unroll
        for (int r = 0; r < 8; r++) m = fmaf(Wproj[o * 64 + h * 8 + r], aw[b][h][r][d], m);
        Mt[(size_t)(b * 64 + (h * 8 + d)) * 64 + o] = m;  // [b][dg][o]
      }
    }
  }
}

// ---------------- K4a: dwconv(v) via LDS + M-matvec + residual + LN2 ----------------
// grid: 4b x 256 rows = 1024 blocks. acc is initialized with x (residual) at entry so
// the 64 x-loads' latency hides under phase A stencil compute; M-matvec accumulates
// on top, giving x1 directly.
__global__ __launch_bounds__(256, 4) void k_cab_out(
    const float* __restrict__ x, const float* __restrict__ kv_pre,
    const float* __restrict__ Wkv_dw, const float* __restrict__ Mt,
    const float* __restrict__ ln2w, const float* __restrict__ ln2b,
    float* __restrict__ x1, unsigned short* __restrict__ xn2b) {
  __shared__ unsigned short vds[64][256];  // 32 KB
  int b = blockIdx.x >> 8;
  int y = blockIdx.x & 255;
  int tid = threadIdx.x;
  int wave = tid >> 6, lane = tid & 63;
  bool ym = y > 0, yp = y < 255;
  int nb = (y << 8) + (lane << 2);
  int n = (y << 8) + tid;

  // residual-as-init: issue 64 coalesced x loads up front
  const float* px = x + (size_t)b * (64 * N_PIX) + n;
  float acc[64];
#pragma unroll
  for (int c = 0; c < 64; c++) acc[c] = px[(size_t)c << 16];

  const float* vb = kv_pre + (size_t)b * (128 * N_PIX) + ((size_t)64 << 16);

  // Phase A: 16 v-channel dwconvs per wave, full row, bf16 -> LDS
#pragma unroll 2
  for (int i = 0; i < 16; i++) {
    int dg = (wave << 4) + i;
    float4 vd = dw3x3v(vb + ((size_t)dg << 16), Wkv_dw + (64 + dg) * 9, nb, lane, ym, yp);
    uint2 u;
    u.x = pk2(vd.x, vd.y);
    u.y = pk2(vd.z, vd.w);
    *reinterpret_cast<uint2*>(&vds[dg][lane << 2]) = u;
  }
  __syncthreads();

  // Phase B: thread per pixel, M-matvec accumulating onto residual
  const float* Mb = Mt + b * 4096;
#pragma unroll 2
  for (int dg = 0; dg < 64; dg++) {
    float v = bf2f(vds[dg][tid]);
    const float* mrow = Mb + dg * 64;
#pragma unroll
    for (int o = 0; o < 64; o++) acc[o] = fmaf(mrow[o], v, acc[o]);
  }
  float* px1 = x1 + (size_t)b * (64 * N_PIX) + n;
  float s1 = 0.f, s2 = 0.f;
#pragma unroll
  for (int c = 0; c < 64; c++) {
    px1[(size_t)c << 16] = acc[c];
    s1 += acc[c];
    s2 = fmaf(acc[c], acc[c], s2);
  }
  float mu = s1 * 0.015625f;
  float var = fmaf(s2, 0.015625f, -mu * mu);
  float rs = rsqrtf(var + 1e-5f);
  unsigned short* pxn = xn2b + ((size_t)b << 24) + ((size_t)n << 6);
#pragma unroll
  for (int c = 0; c < 64; c += 8) {
    float t0 = fmaf((acc[c + 0] - mu) * rs, ln2w[c + 0], ln2b[c + 0]);
    float t1 = fmaf((acc[c + 1] - mu) * rs, ln2w[c + 1], ln2b[c + 1]);
    float t2 = fmaf((acc[c + 2] - mu) * rs, ln2w[c + 2], ln2b[c + 2]);
    float t3 = fmaf((acc[c + 3] - mu) * rs, ln2w[c + 3], ln2b[c + 3]);
    float t4 = fmaf((acc[c + 4] - mu) * rs, ln2w[c + 4], ln2b[c + 4]);
    float t5 = fmaf((acc[c + 5] - mu) * rs, ln2w[c + 5], ln2b[c + 5]);
    float t6 = fmaf((acc[c + 6] - mu) * rs, ln2w[c + 6], ln2b[c + 6]);
    float t7 = fmaf((acc[c + 7] - mu) * rs, ln2w[c + 7], ln2b[c + 7]);
    uint4 u;
    u.x = pk2(t0, t1); u.y = pk2(t2, t3); u.z = pk2(t4, t5); u.w = pk2(t6, t7);
    *reinterpret_cast<uint4*>(pxn + c) = u;
  }
}

// ---------------- K4b: MFMA FFN: xn2 -> W12 -> silu-gate -> W3 -> +x1 -> out ----------------
__global__ __launch_bounds__(256) void k_ffn(
    const float* __restrict__ x1, const unsigned short* __restrict__ xn2b,
    const unsigned short* __restrict__ W12s, const unsigned short* __restrict__ W3s,
    float* __restrict__ outp) {
  __shared__ unsigned short g_all[4][32 * 200];  // 51.2 KB
  int b = blockIdx.x >> 9;
  int pblk = (blockIdx.x & 511) << 7;
  int w = threadIdx.x >> 6;
  int l = threadIdx.x & 63;
  int pix0 = pblk + (w << 5);
  int lrow = l & 15, lgrp = l >> 4;
  unsigned short* gl = &g_all[w][0];

  {
    unsigned int* gz = (unsigned int*)(gl + (size_t)(l & 31) * 200);
    int base = 88 + ((l >> 5) << 2);
    gz[base] = 0u; gz[base + 1] = 0u; gz[base + 2] = 0u; gz[base + 3] = 0u;
  }

  const unsigned short* xn2 = xn2b + ((size_t)b << 24);
  bf16x8 a1[2][2];
#pragma unroll
  for (int mt = 0; mt < 2; mt++)
#pragma unroll
    for (int kk = 0; kk < 2; kk++)
      a1[mt][kk] = *(const bf16x8*)(xn2 + (((size_t)(pix0 + mt * 16 + lrow)) << 6) + (kk << 5) + (lgrp << 3));

#pragma unroll 1
  for (int nt = 0; nt < 11; nt++) {
    f32x4 h1[2], h2[2];
#pragma unroll
    for (int mt = 0; mt < 2; mt++) {
      h1[mt] = (f32x4){0.f, 0.f, 0.f, 0.f};
      h2[mt] = (f32x4){0.f, 0.f, 0.f, 0.f};
    }
#pragma unroll
    for (int kk = 0; kk < 2; kk++) {
      bf16x8 b1 = *(const bf16x8*)(W12s + ((((nt << 1) + kk) << 6) + l) * 8);
      bf16x8 b2 = *(const bf16x8*)(W12s + (((((nt + 11) << 1) + kk) << 6) + l) * 8);
#pragma unroll
      for (int mt = 0; mt < 2; mt++) {
        h1[mt] = __builtin_amdgcn_mfma_f32_16x16x32_bf16(a1[mt][kk], b1, h1[mt], 0, 0, 0);
        h2[mt] = __builtin_amdgcn_mfma_f32_16x16x32_bf16(a1[mt][kk], b2, h2[mt], 0, 0, 0);
      }
    }
#pragma unroll
    for (int mt = 0; mt < 2; mt++)
#pragma unroll
      for (int r = 0; r < 4; r++) {
        float hh1 = h1[mt][r], hh2 = h2[mt][r];
        float g = hh1 * __builtin_amdgcn_rcpf(1.f + __expf(-hh1)) * hh2;
        gl[(mt * 16 + (lgrp << 2) + r) * 200 + nt * 16 + lrow] = f2bf(g);
      }
  }
  __syncthreads();

  f32x4 acc[2][4];
#pragma unroll
  for (int mt = 0; mt < 2; mt++)
#pragma unroll
    for (int nt2 = 0; nt2 < 4; nt2++) acc[mt][nt2] = (f32x4){0.f, 0.f, 0.f, 0.f};
#pragma unroll 1
  for (int kk = 0; kk < 6; kk++) {
    bf16x8 a2[2];
#pragma unroll
    for (int mt = 0; mt < 2; mt++)
      a2[mt] = *(const bf16x8*)(gl + (mt * 16 + lrow) * 200 + (kk << 5) + (lgrp << 3));
#pragma unroll
    for (int nt2 = 0; nt2 < 4; nt2++) {
      bf16x8 b3 = *(const bf16x8*)(W3s + (((nt2 * 6 + kk) << 6) + l) * 8);
#pragma unroll
      for (int mt = 0; mt < 2; mt++)
        acc[mt][nt2] = __builtin_amdgcn_mfma_f32_16x16x32_bf16(a2[mt], b3, acc[mt][nt2], 0, 0, 0);
    }
  }
  __syncthreads();

  float* ol = (float*)gl;  // [32][67] f32
#pragma unroll
  for (int mt = 0; mt < 2; mt++)
#pragma unroll
    for (int nt2 = 0; nt2 < 4; nt2++)
#pragma unroll
      for (int r = 0; r < 4; r++)
        ol[(mt * 16 + (lgrp << 2) + r) * 67 + nt2 * 16 + lrow] = acc[mt][nt2][r];
  __syncthreads();

#pragma unroll 2
  for (int it = 0; it < 32; it++) {
    int o = (it << 1) + (l >> 5);
    int p = l & 31;
    size_t gi = (((size_t)b << 6) + (size_t)o) * N_PIX + (size_t)(pix0 + p);
    outp[gi] = x1[gi] + ol[p * 67 + o];
  }
}

extern "C" void kernel_launch(void* const* d_in, const int* in_sizes, int n_in,
                              void* d_out, int out_size, void* d_ws, size_t ws_size,
                              hipStream_t stream) {
  const float* x      = (const float*)d_in[0];
  const float* y      = (const float*)d_in[1];
  const float* ln1xw  = (const float*)d_in[2];
  const float* ln1xb  = (const float*)d_in[3];
  const float* ln1yw  = (const float*)d_in[4];
  const float* ln1yb  = (const float*)d_in[5];
  const float* ln2w   = (const float*)d_in[6];
  const float* ln2b   = (const float*)d_in[7];
  const float* Wq     = (const float*)d_in[8];
  const float* Wq_dw  = (const float*)d_in[9];
  const float* Wkv    = (const float*)d_in[10];
  const float* Wkv_dw = (const float*)d_in[11];
  const float* Wproj  = (const float*)d_in[12];
  const float* temp   = (const float*)d_in[13];
  const float* W12    = (const float*)d_in[14];
  const float* W3     = (const float*)d_in[15];
  float* out = (float*)d_out;
  float* ws = (float*)d_ws;

  float* q_pre  = ws + OFF_QPRE;
  float* kv_pre = ws + OFF_KVPRE;
  float* Sb     = ws + OFF_S;
  float* sqb    = ws + OFF_SQ;
  float* skb    = ws + OFF_SK;
  float* Mt     = ws + OFF_MT;
  float* x1     = ws + OFF_QPRE;                             // q_pre dead after k_qk_stats
  unsigned short* xn2b = (unsigned short*)(ws + OFF_KVPRE);  // k-half dead after k_qk_stats

  k_prep<<<64, 256, 0, stream>>>(Wq, ln1xw, ln1xb, Wkv, ln1yw, ln1yb, W12, W3, ws);
  k_ln_conv_q<<<1024, 256, 0, stream>>>(x, ws + OFF_WQT, ws + OFF_BQ, ws + OFF_CQ, q_pre);
  k_ln_conv_kv<<<1024, 256, 0, stream>>>(y, ws + OFF_WKVT, ws + OFF_BKV, ws + OFF_CKV, kv_pre);
  k_qk_stats<<<2048, 256, 0, stream>>>(q_pre, kv_pre, Wq_dw, Wkv_dw, Sb, sqb, skb);
  k_attn_mat<<<1, 256, 0, stream>>>(Sb, sqb, skb, temp, Wproj, Mt);
  k_cab_out<<<1024, 256, 0, stream>>>(x, kv_pre, Wkv_dw, Mt, ln2w, ln2b, x1, xn2b);
  k_ffn<<<2048, 256, 0, stream>>>(x1, xn2b, (unsigned short*)(ws + OFF_W12S),
                                  (unsigned short*)(ws + OFF_W3S), out);
}